// Round 12
// baseline (746.560 us; speedup 1.0000x reference)
//
#include <hip/hip_runtime.h>
#include <stdio.h>

// ---------------------------------------------------------------------------
// WindowAttention: partition -> QKV gemm -> attention over B axis ->
// fused (out_proj @ mlp) gemm with window-reverse scatter epilogue.
// GEMM: 256x256, v_mfma_f32_32x32x16_bf16 (higher ceiling, half the MFMA
// instruction count vs 16x16x32); A staged via LDS (swizzled global_load_lds),
// B direct-from-global in fragment-prepacked layout. r9 staging skeleton.
// ---------------------------------------------------------------------------

typedef __attribute__((ext_vector_type(4))) float f32x4;
typedef __attribute__((ext_vector_type(16))) float f32x16;
typedef __attribute__((ext_vector_type(8))) short s16x8;
typedef __attribute__((ext_vector_type(2))) unsigned short u16x2;
typedef __attribute__((ext_vector_type(4))) unsigned short u16x4;

#define NB 4        // batch B (attention seq len)
#define NC 32       // channels
#define NTOK 4096   // N = 16^3 windows
#define ED 2048     // embed dim E
#define NH 16       // heads
#define HD 128      // head dim

__device__ __forceinline__ unsigned short f2bf(float f) {
    union { float f; unsigned int u; } v; v.f = f;
    unsigned int r = (v.u + 0x7fffu + ((v.u >> 16) & 1u)) >> 16;
    return (unsigned short)r;
}
__device__ __forceinline__ float bf2f(unsigned short u) {
    union { unsigned int u; float f; } v; v.u = ((unsigned int)u) << 16;
    return v.f;
}

#define BARRIER() asm volatile("s_barrier" ::: "memory")
#define LGKM0() do { asm volatile("s_waitcnt lgkmcnt(0)" ::: "memory"); \
                     __builtin_amdgcn_sched_barrier(0); } while (0)
#define LGKM8() do { asm volatile("s_waitcnt lgkmcnt(8)" ::: "memory"); \
                     __builtin_amdgcn_sched_barrier(0); } while (0)
#define VMCNT(n) asm volatile("s_waitcnt vmcnt(" #n ")" ::: "memory")

// ---------------- fp32 -> bf16 convert (weights) ----------------
__global__ void f32_to_bf16_kernel(const float* __restrict__ src,
                                   unsigned short* __restrict__ dst, int n4) {
    int i = blockIdx.x * blockDim.x + threadIdx.x;
    if (i >= n4) return;
    f32x4 v = *(const f32x4*)(src + (size_t)i * 4);
    u16x4 w;
    w.x = f2bf(v.x); w.y = f2bf(v.y); w.z = f2bf(v.z); w.w = f2bf(v.w);
    *(u16x4*)(dst + (size_t)i * 4) = w;
}

// ---------------- transpose f32 -> bf16: dst[j,k] = src[k,j] ----------------
__global__ __launch_bounds__(256) void transpose_bf16_kernel(
    const float* __restrict__ src, unsigned short* __restrict__ dst, int n) {
    __shared__ float lds[64][68];
    const int bx = blockIdx.x * 64;   // j base
    const int by = blockIdx.y * 64;   // k base
    const int t  = threadIdx.x;
    const int r  = t >> 2;            // 0..63
    const int c4 = (t & 3) * 16;      // 0/16/32/48
    const float* s = src + (size_t)(by + r) * n + bx + c4;
    #pragma unroll
    for (int i = 0; i < 4; ++i)
        *(f32x4*)&lds[r][c4 + i * 4] = *(const f32x4*)(s + i * 4);
    __syncthreads();
    unsigned short* d = dst + (size_t)(bx + r) * n + by + c4;
    #pragma unroll
    for (int i = 0; i < 4; ++i) {
        u16x4 w;
        w.x = f2bf(lds[c4 + i * 4 + 0][r]);
        w.y = f2bf(lds[c4 + i * 4 + 1][r]);
        w.z = f2bf(lds[c4 + i * 4 + 2][r]);
        w.w = f2bf(lds[c4 + i * 4 + 3][r]);
        *(u16x4*)(d + i * 4) = w;
    }
}

// ---------------- pack weights into 32x32x16-fragment-major layout ---------
// src (Nout x K row-major) -> dst: for each (strip=Nout/64, kt=K/64):
// 8 frags (fid = ks*2 + nblk, ks=kstep 0..3, nblk 0..1), 64 lanes x 16B:
//   lane l holds W[strip*64 + nblk*32 + (l&31)][kt*64 + ks*16 + (l>>5)*8 + e]
template <int SRC_F32>
__global__ __launch_bounds__(512) void pack_w_kernel(
    const void* __restrict__ src, unsigned short* __restrict__ dst, int K) {
    __shared__ unsigned short lds[64][72];   // row stride 144B (16B-aligned)
    const int nkt   = K >> 6;
    const int strip = blockIdx.x;
    const int kt    = blockIdx.y;
    const int t     = threadIdx.x;
    {
        const int r = t >> 3, c8 = (t & 7) * 8;
        if (SRC_F32) {
            const float* s = (const float*)src + (size_t)(strip * 64 + r) * K + kt * 64 + c8;
            f32x4 a = *(const f32x4*)s, b = *(const f32x4*)(s + 4);
            u16x4 w0, w1;
            w0.x = f2bf(a.x); w0.y = f2bf(a.y); w0.z = f2bf(a.z); w0.w = f2bf(a.w);
            w1.x = f2bf(b.x); w1.y = f2bf(b.y); w1.z = f2bf(b.z); w1.w = f2bf(b.w);
            *(u16x4*)&lds[r][c8] = w0; *(u16x4*)&lds[r][c8 + 4] = w1;
        } else {
            const unsigned short* s = (const unsigned short*)src + (size_t)(strip * 64 + r) * K + kt * 64 + c8;
            *(s16x8*)&lds[r][c8] = *(const s16x8*)s;
        }
    }
    __syncthreads();
    const int fid = t >> 6, lane = t & 63;
    const int nblk = fid & 1, ks = fid >> 1;
    const int lrow32 = lane & 31, khi = lane >> 5;
    s16x8 v = *(const s16x8*)&lds[nblk * 32 + lrow32][ks * 16 + khi * 8];
    size_t off = (((size_t)strip * nkt + kt) * 8 + fid) * 512 + lane * 8;
    *(s16x8*)&dst[off] = v;
}

// ---------------- b_comb = mlp_w @ out_proj_b + mlp_b (wave per row) -------
__global__ __launch_bounds__(256) void bcomb_kernel(
    const float* __restrict__ mlp_w, const float* __restrict__ opb,
    const float* __restrict__ mlpb, float* __restrict__ bcomb) {
    const int wave = threadIdx.x >> 6, lane = threadIdx.x & 63;
    const int row = blockIdx.x * 4 + wave;
    const float* r = mlp_w + (size_t)row * ED;
    float s = 0.0f;
    for (int k = lane * 4; k < ED; k += 256) {
        f32x4 a = *(const f32x4*)(r + k);
        f32x4 b = *(const f32x4*)(opb + k);
        s += a.x * b.x + a.y * b.y + a.z * b.z + a.w * b.w;
    }
    #pragma unroll
    for (int off = 32; off > 0; off >>= 1) s += __shfl_xor(s, off, 64);
    if (lane == 0) bcomb[row] = s + mlpb[row];
}

// ---------------- window partition: x -> tok (B,N,E) bf16 ----------------
__global__ void partition_kernel(const float* __restrict__ x,
                                 unsigned short* __restrict__ tok) {
    int idx = blockIdx.x * blockDim.x + threadIdx.x;
    int m = idx & 15;
    int t = idx >> 4;
    int Y = t & 63; t >>= 6;
    int X = t & 63; t >>= 6;
    int c = t & 31;
    int b = t >> 5;
    f32x4 xv = *(const f32x4*)(x + (size_t)idx * 4);
    int nx = X >> 2, px = X & 3;
    int ny = Y >> 2, py = Y & 3;
    int n = nx * 256 + ny * 16 + m;
    int e = c * 64 + px * 16 + py * 4;
    size_t dst = (size_t)(b * NTOK + n) * ED + e;
    u16x4 w;
    w.x = f2bf(xv.x); w.y = f2bf(xv.y); w.z = f2bf(xv.z); w.w = f2bf(xv.w);
    *(u16x4*)&tok[dst] = w;
}

// ---------------- 128x128 4-wave bf16 GEMM (for small W_comb job) ----------
__global__ __launch_bounds__(256) void gemm128(
    const unsigned short* __restrict__ A,   // M x K bf16
    const unsigned short* __restrict__ W,   // Nout x K bf16
    const float* __restrict__ bias,         // Nout f32
    unsigned short* __restrict__ C,         // M x Nout bf16
    int M, int Nout, int K)
{
    __shared__ unsigned short ldsA[128 * 64];
    __shared__ unsigned short ldsW[128 * 64];

    const int tid  = threadIdx.x;
    const int wave = tid >> 6;
    const int lane = tid & 63;
    const int bm = blockIdx.x * 128;
    const int bn = blockIdx.y * 128;
    const int wm = (wave >> 1) * 64;
    const int wn = (wave & 1) * 64;

    f32x4 acc[4][4] = {};

    const int srow = lane >> 3;
    const int scol = (lane & 7) * 8;
    const int lrow = lane & 15;
    const int lk   = (lane >> 4) * 8;

    const int nkt = K >> 6;
    for (int kt = 0; kt < nkt; ++kt) {
        const int kbase = kt * 64;
        #pragma unroll
        for (int q = 0; q < 4; ++q) {
            int chunk = wave * 4 + q;
            int row = chunk * 8 + srow;
            const unsigned short* ga = A + (size_t)(bm + row) * K + kbase + scol;
            const unsigned short* gw = W + (size_t)(bn + row) * K + kbase + scol;
            __builtin_amdgcn_global_load_lds(
                (const __attribute__((address_space(1))) void*)ga,
                (__attribute__((address_space(3))) void*)(&ldsA[chunk * 512]),
                16, 0, 0);
            __builtin_amdgcn_global_load_lds(
                (const __attribute__((address_space(1))) void*)gw,
                (__attribute__((address_space(3))) void*)(&ldsW[chunk * 512]),
                16, 0, 0);
        }
        __syncthreads();

        #pragma unroll
        for (int ks = 0; ks < 2; ++ks) {
            const int k0 = ks * 32 + lk;
            s16x8 af[4], bf[4];
            #pragma unroll
            for (int m = 0; m < 4; ++m)
                af[m] = *(const s16x8*)&ldsA[(wm + m * 16 + lrow) * 64 + k0];
            #pragma unroll
            for (int n = 0; n < 4; ++n)
                bf[n] = *(const s16x8*)&ldsW[(wn + n * 16 + lrow) * 64 + k0];
            #pragma unroll
            for (int m = 0; m < 4; ++m)
                #pragma unroll
                for (int n = 0; n < 4; ++n)
                    acc[m][n] = __builtin_amdgcn_mfma_f32_16x16x32_bf16(
                        af[m], bf[n], acc[m][n], 0, 0, 0);
        }
        __syncthreads();
    }

    const int col   = lane & 15;
    const int rbase = (lane >> 4) * 4;
    #pragma unroll
    for (int n = 0; n < 4; ++n) {
        int cc = bn + wn + n * 16 + col;
        float bv = bias[cc];
        #pragma unroll
        for (int m = 0; m < 4; ++m)
            #pragma unroll
            for (int r = 0; r < 4; ++r) {
                int rr = bm + wm + m * 16 + rbase + r;
                C[(size_t)rr * Nout + cc] = f2bf(acc[m][n][r] + bv);
            }
    }
}

// ---------------- 256x256 GEMM, 32x32x16 MFMA, B direct-from-global -------
// C[r,j] = sum_k A[r,k] * W[j,k] + bias[j].  M == 16384, Nout % 1024 == 0.
// 8 waves (2M x 4N), per-wave 128x64 = 4m x 2n blocks of 32x32.
// A frag (m,ks): lane l holds A[m*32+(l&31)][ks*16+(l>>5)*8+e] (b128 from
// swizzled LDS). B frag (ks,nblk) prepacked (pack_w_kernel). Per tile t:
// E1=loadBk0(t+1), E2=stA(t+2), E3=loadBk1(t+1); W1/W2=vmcnt(8) as in r9.
// C/D layout: col=lane&31, row=(reg&3)+8*(reg>>2)+4*(lane>>5).
// OUT_MODE: 1 = bf16 row-major; 2 = f32 window-reverse scatter.
template <int OUT_MODE>
__global__ __launch_bounds__(512, 2) void gemm256(
    const unsigned short* __restrict__ A,   // M x K bf16 row-major
    const unsigned short* __restrict__ Bp,  // packed weights
    const float* __restrict__ bias,         // Nout f32
    void* __restrict__ Cv,                  // out per OUT_MODE
    int M, int Nout, int K)
{
    __shared__ unsigned short ldsA[2][2][128 * 64];

    const int tid  = threadIdx.x;
    const int wave = tid >> 6;
    const int lane = tid & 63;

    // L2-locality mapping (bijective, gm=64): XCD x owns m-band x; 8m x 4n
    // macro-tiles of 32 blocks = the concurrent set per XCD.
    const int f   = blockIdx.x;
    const int xcd = f & 7;
    const int r_  = f >> 3;
    const int mac = r_ >> 5;
    const int w_  = r_ & 31;
    const int bm  = (xcd * 8 + (w_ & 7)) * 256;
    const int bn  = (mac * 4 + (w_ >> 3)) * 256;

    const int wi     = wave >> 2;        // 0/1: M half
    const int wj     = wave & 3;         // 0-3: N quarter
    const int lrow32 = lane & 31;
    const int khi    = lane >> 5;        // k-group 0/1

    f32x16 acc[4][2] = {};               // [m-block][n-block], 32x32 each

    const int nkt = K >> 6;
    const unsigned short* Bbase =
        Bp + ((size_t)((bn >> 6) + wj) * nkt) * 4096 + lane * 8;

    const int srl   = lane >> 3;                         // 0-7
    const int sslot = (((lane & 7) ^ srl) << 3);         // pre-swizzled src off

    auto stA = [&](int db, int half, int tt) {
        const unsigned short* gb = A + (size_t)(bm + half * 128) * K + tt * 64;
        unsigned short* lb = &ldsA[db][half][0];
        #pragma unroll
        for (int q = 0; q < 2; ++q) {
            const int r0 = wave * 16 + q * 8;
            const unsigned short* ga = gb + (size_t)(r0 + srl) * K + sslot;
            __builtin_amdgcn_global_load_lds(
                (const __attribute__((address_space(1))) void*)ga,
                (__attribute__((address_space(3))) void*)(lb + r0 * 64),
                16, 0, 0);
        }
    };

    // A-read address helper: frag (m, ks) -> elem offset in half-tile LDS
    // row = m*32 + lrow32; global slot = 2*ks + khi; stored slot ^= row&7
    int arow[4], asw[4];
    #pragma unroll
    for (int m = 0; m < 4; ++m) {
        arow[m] = (m * 32 + lrow32) * 64;
        asw[m]  = (m * 32 + lrow32) & 7;
    }

    s16x8 A0[8], A1[8], Bk0[4], Bk1[4];  // A[ks*4+m], B[ks*2+nb] per half

    // ---- prologue: A(0)->db0, A(1)->db1, B(0) both halves
    stA(0, 0, 0); stA(0, 1, 0);
    stA(1, 0, 1); stA(1, 1, 1);
    {
        const unsigned short* fb = Bbase;   // kt = 0
        #pragma unroll
        for (int j = 0; j < 4; ++j) Bk0[j] = *(const s16x8*)(fb + j * 512);
        #pragma unroll
        for (int j = 0; j < 4; ++j) Bk1[j] = *(const s16x8*)(fb + (4 + j) * 512);
    }
    VMCNT(0);
    BARRIER();

    for (int t = 0; t < nkt; ++t) {
        const int db = t & 1;
        const unsigned short* hA = &ldsA[db][wi][0];
        const unsigned short* fbn = Bbase + (size_t)(t + 1) * 4096;

        // A reads: kh0 (ks=0,1) then kh1 (ks=2,3), 8 b128 each
        #pragma unroll
        for (int ks = 0; ks < 2; ++ks)
            #pragma unroll
            for (int m = 0; m < 4; ++m)
                A0[ks * 4 + m] = *(const s16x8*)&hA[arow[m] + (((2 * ks + khi) ^ asw[m]) << 3)];
        #pragma unroll
        for (int ks = 0; ks < 2; ++ks)
            #pragma unroll
            for (int m = 0; m < 4; ++m)
                A1[ks * 4 + m] = *(const s16x8*)&hA[arow[m] + (((2 * (ks + 2) + khi) ^ asw[m]) << 3)];

        // W1: Bk0(t) resident
        if (t + 2 < nkt) { VMCNT(8); } else { VMCNT(0); }
        LGKM8();   // A0 resident (oldest 8 of 16 ds_reads)
        __builtin_amdgcn_s_setprio(1);
        #pragma unroll
        for (int ks = 0; ks < 2; ++ks)
            #pragma unroll
            for (int m = 0; m < 4; ++m)
                #pragma unroll
                for (int nb = 0; nb < 2; ++nb)
                    acc[m][nb] = __builtin_amdgcn_mfma_f32_32x32x16_bf16(
                        A0[ks * 4 + m], Bk0[ks * 2 + nb], acc[m][nb], 0, 0, 0);
        __builtin_amdgcn_s_setprio(0);

        // E1: next-tile Bk0 (WAR on Bk0 regs keeps this after the MFMAs)
        if (t + 1 < nkt) {
            #pragma unroll
            for (int j = 0; j < 4; ++j) Bk0[j] = *(const s16x8*)(fbn + j * 512);
        }

        LGKM0();   // A1 resident (drained under kh0 MFMAs)
        BARRIER(); // #1: all waves done reading db

        // E2: stage A(t+2) -> db
        if (t + 2 < nkt) { stA(db, 0, t + 2); stA(db, 1, t + 2); }

        // W2: Bk1(t) + stA(t+1) resident
        if (t + 2 < nkt) { VMCNT(8); } else { VMCNT(0); }
        __builtin_amdgcn_s_setprio(1);
        #pragma unroll
        for (int ks = 0; ks < 2; ++ks)
            #pragma unroll
            for (int m = 0; m < 4; ++m)
                #pragma unroll
                for (int nb = 0; nb < 2; ++nb)
                    acc[m][nb] = __builtin_amdgcn_mfma_f32_32x32x16_bf16(
                        A1[ks * 4 + m], Bk1[ks * 2 + nb], acc[m][nb], 0, 0, 0);
        __builtin_amdgcn_s_setprio(0);

        // E3: next-tile Bk1
        if (t + 1 < nkt) {
            #pragma unroll
            for (int j = 0; j < 4; ++j) Bk1[j] = *(const s16x8*)(fbn + (4 + j) * 512);
        }
        BARRIER(); // #2: tile t+1 A resident everywhere (drained at W2)
    }

    // ---- epilogue: C/D col=lane&31, row=(reg&3)+8*(reg>>2)+4*(lane>>5)
    const int rowbase = bm + wi * 128;
    float bv[2];
    #pragma unroll
    for (int nb = 0; nb < 2; ++nb)
        bv[nb] = bias[bn + wj * 64 + nb * 32 + lrow32];

    if (OUT_MODE == 1) {
        unsigned short* C = (unsigned short*)Cv;
        #pragma unroll
        for (int m = 0; m < 4; ++m) {
            #pragma unroll
            for (int nb = 0; nb < 2; ++nb) {
                const int cc = bn + wj * 64 + nb * 32 + lrow32;
                #pragma unroll
                for (int rg = 0; rg < 4; ++rg) {
                    const int r0 = rowbase + m * 32 + rg * 8 + 4 * khi;
                    #pragma unroll
                    for (int j = 0; j < 4; ++j)
                        C[(size_t)(r0 + j) * Nout + cc] = f2bf(acc[m][nb][rg * 4 + j] + bv[nb]);
                }
            }
        }
    } else {
        // window-reverse scatter: rr=(b,nx,ny,nz), cc=(c,px,py,pz) ->
        // out[b,c, px*16+nx, py*16+ny, pz*16+nz]; 4 consecutive regs = nz run
        float* outp = (float*)Cv;
        #pragma unroll
        for (int nb = 0; nb < 2; ++nb) {
            const int cc = bn + wj * 64 + nb * 32 + lrow32;
            const int c  = cc >> 6, px = (cc >> 4) & 3,
                      py = (cc >> 2) & 3, pz = cc & 3;
            #pragma unroll
            for (int m = 0; m < 4; ++m) {
                #pragma unroll
                for (int rg = 0; rg < 4; ++rg) {
                    const int rr0 = rowbase + m * 32 + rg * 8 + 4 * khi;
                    const int b   = rr0 >> 12, nx = (rr0 >> 8) & 15,
                              ny  = (rr0 >> 4) & 15, nz0 = rr0 & 15;
                    float* dst = outp
                        + ((size_t)((b * NC + c) * 64 + px * 16 + nx)) * 4096
                        + (size_t)(py * 16 + ny) * 64 + pz * 16 + nz0;
                    f32x4 w = {acc[m][nb][rg * 4 + 0] + bv[nb],
                               acc[m][nb][rg * 4 + 1] + bv[nb],
                               acc[m][nb][rg * 4 + 2] + bv[nb],
                               acc[m][nb][rg * 4 + 3] + bv[nb]};
                    *(f32x4*)dst = w;
                }
            }
        }
    }
}

// ---------------- attention over B axis: seq=4, batch = N*H ----------------
// block = token n (4096 blocks, 512 thr); wave handles 2 heads; u16x4 loads.
__global__ __launch_bounds__(512) void attn_kernel(
    const unsigned short* __restrict__ qkv, unsigned short* __restrict__ o)
{
    const int n    = blockIdx.x;
    const int wave = threadIdx.x >> 6;
    const int lane = threadIdx.x & 63;
    const int h    = wave * 2 + (lane >> 5);
    const int dl   = (lane & 31) * 4;
    const float scale = 0.0883883476483184405501f;  // 1/sqrt(128)

    float q[4][4], k[4][4], v[4][4];
    #pragma unroll
    for (int b = 0; b < 4; ++b) {
        size_t base = (size_t)(b * NTOK + n) * (3 * ED) + h * HD + dl;
        u16x4 uq = *(const u16x4*)&qkv[base];
        u16x4 uk = *(const u16x4*)&qkv[base + ED];
        u16x4 uv = *(const u16x4*)&qkv[base + 2 * ED];
        #pragma unroll
        for (int i = 0; i < 4; ++i) {
            q[b][i] = bf2f(uq[i]); k[b][i] = bf2f(uk[i]); v[b][i] = bf2f(uv[i]);
        }
    }

    float sc[4][4];
    #pragma unroll
    for (int s = 0; s < 4; ++s) {
        #pragma unroll
        for (int t = 0; t < 4; ++t) {
            float p = q[s][0] * k[t][0] + q[s][1] * k[t][1]
                    + q[s][2] * k[t][2] + q[s][3] * k[t][3];
            #pragma unroll
            for (int off = 16; off > 0; off >>= 1)   // reduce within 32-group
                p += __shfl_xor(p, off, 64);
            sc[s][t] = p * scale;
        }
    }

    #pragma unroll
    for (int s = 0; s < 4; ++s) {
        float mx = fmaxf(fmaxf(sc[s][0], sc[s][1]), fmaxf(sc[s][2], sc[s][3]));
        float e0 = __expf(sc[s][0] - mx);
        float e1 = __expf(sc[s][1] - mx);
        float e2 = __expf(sc[s][2] - mx);
        float e3 = __expf(sc[s][3] - mx);
        float inv = 1.0f / (e0 + e1 + e2 + e3);
        u16x4 ov;
        #pragma unroll
        for (int i = 0; i < 4; ++i) {
            float oo = (e0 * v[0][i] + e1 * v[1][i] + e2 * v[2][i] + e3 * v[3][i]) * inv;
            ov[i] = f2bf(oo);
        }
        *(u16x4*)&o[(size_t)(s * NTOK + n) * ED + h * HD + dl] = ov;
    }
}

// ---------------------------------------------------------------------------
extern "C" void kernel_launch(void* const* d_in, const int* in_sizes, int n_in,
                              void* d_out, int out_size, void* d_ws, size_t ws_size,
                              hipStream_t stream) {
    const float* x          = (const float*)d_in[0];
    const float* in_proj_w  = (const float*)d_in[1];
    const float* in_proj_b  = (const float*)d_in[2];
    const float* out_proj_w = (const float*)d_in[3];
    const float* out_proj_b = (const float*)d_in[4];
    const float* mlp_w      = (const float*)d_in[5];
    const float* mlp_b      = (const float*)d_in[6];
    float* out = (float*)d_out;

    const size_t M = 16384;                       // B*N rows
    char* ws = (char*)d_ws;
    size_t off = 0;
    unsigned short* tok     = (unsigned short*)(ws + off); off += M * ED * 2;
    unsigned short* w_inP   = (unsigned short*)(ws + off); off += (size_t)3 * ED * ED * 2;
    unsigned short* w_mlp   = (unsigned short*)(ws + off); off += (size_t)ED * ED * 2;
    unsigned short* w_outT  = (unsigned short*)(ws + off); off += (size_t)ED * ED * 2;
    unsigned short* w_comb  = (unsigned short*)(ws + off); off += (size_t)ED * ED * 2;
    unsigned short* w_combP = (unsigned short*)(ws + off); off += (size_t)ED * ED * 2;
    float* zbias            = (float*)(ws + off);          off += ED * 4;
    float* b_comb           = (float*)(ws + off);          off += ED * 4;
    unsigned short* obuf    = (unsigned short*)(ws + off); off += M * ED * 2;
    unsigned short* qkv     = (unsigned short*)(ws + off); off += M * 3 * ED * 2;

    if (ws_size < off) {
        fprintf(stderr, "kernel_launch: ws too small (%zu < %zu)\n", ws_size, off);
        return;
    }

    // weight prep: pack in_proj (fused f32->bf16), convert mlp, transpose out
    pack_w_kernel<1><<<dim3(3 * ED / 64, ED / 64), 512, 0, stream>>>(
        in_proj_w, w_inP, ED);
    {
        int n4 = ED * ED / 4;
        f32_to_bf16_kernel<<<(n4 + 255) / 256, 256, 0, stream>>>(mlp_w, w_mlp, n4);
        transpose_bf16_kernel<<<dim3(ED / 64, ED / 64), 256, 0, stream>>>(
            out_proj_w, w_outT, ED);
        hipMemsetAsync(zbias, 0, ED * sizeof(float), stream);
    }

    // W_comb = mlp_w @ out_proj_w  (row-major [j][k]); then pack
    gemm128<<<dim3(ED / 128, ED / 128), 256, 0, stream>>>(
        w_mlp, w_outT, zbias, w_comb, ED, ED, ED);
    pack_w_kernel<0><<<dim3(ED / 64, ED / 64), 512, 0, stream>>>(
        w_comb, w_combP, ED);
    // b_comb = mlp_w @ out_proj_b + mlp_b
    bcomb_kernel<<<ED / 4, 256, 0, stream>>>(mlp_w, out_proj_b, mlp_b, b_comb);

    // window partition
    partition_kernel<<<(NB * NC * 64 * 64 * 16) / 256, 256, 0, stream>>>(x, tok);

    // qkv = tok @ in_proj_w^T + in_proj_b   (16384 x 6144 x 2048)
    gemm256<1><<<dim3(64 * (6144 / 256)), 512, 0, stream>>>(
        tok, w_inP, in_proj_b, qkv, 16384, 6144, 2048);

    // attention (seq=B=4, batch=N*H)
    attn_kernel<<<NTOK, 512, 0, stream>>>(qkv, obuf);

    // out = reverse(obuf @ W_comb^T + b_comb)  -- scatter epilogue
    gemm256<2><<<dim3(64 * (2048 / 256)), 512, 0, stream>>>(
        obuf, w_combP, b_comb, out, 16384, 2048, 2048);
}

// Round 13
// 745.468 us; speedup vs baseline: 1.0015x; 1.0015x over previous
//
#include <hip/hip_runtime.h>
#include <stdio.h>

// ---------------------------------------------------------------------------
// WindowAttention: partition -> QKV gemm -> attention over B axis ->
// fused (out_proj @ mlp) gemm with window-reverse scatter epilogue.
// GEMM: 256x256, v_mfma_f32_32x32x16_bf16 (higher ceiling, half the MFMA
// instruction count vs 16x16x32); A staged via LDS (swizzled global_load_lds),
// B direct-from-global in fragment-prepacked layout. r9 staging skeleton.
// ---------------------------------------------------------------------------

typedef __attribute__((ext_vector_type(4))) float f32x4;
typedef __attribute__((ext_vector_type(16))) float f32x16;
typedef __attribute__((ext_vector_type(8))) short s16x8;
typedef __attribute__((ext_vector_type(2))) unsigned short u16x2;
typedef __attribute__((ext_vector_type(4))) unsigned short u16x4;

#define NB 4        // batch B (attention seq len)
#define NC 32       // channels
#define NTOK 4096   // N = 16^3 windows
#define ED 2048     // embed dim E
#define NH 16       // heads
#define HD 128      // head dim

__device__ __forceinline__ unsigned short f2bf(float f) {
    union { float f; unsigned int u; } v; v.f = f;
    unsigned int r = (v.u + 0x7fffu + ((v.u >> 16) & 1u)) >> 16;
    return (unsigned short)r;
}
__device__ __forceinline__ float bf2f(unsigned short u) {
    union { unsigned int u; float f; } v; v.u = ((unsigned int)u) << 16;
    return v.f;
}

#define BARRIER() asm volatile("s_barrier" ::: "memory")
#define LGKM0() do { asm volatile("s_waitcnt lgkmcnt(0)" ::: "memory"); \
                     __builtin_amdgcn_sched_barrier(0); } while (0)
#define LGKM8() do { asm volatile("s_waitcnt lgkmcnt(8)" ::: "memory"); \
                     __builtin_amdgcn_sched_barrier(0); } while (0)
#define VMCNT(n) asm volatile("s_waitcnt vmcnt(" #n ")" ::: "memory")

// ---------------- fp32 -> bf16 convert (weights) ----------------
__global__ void f32_to_bf16_kernel(const float* __restrict__ src,
                                   unsigned short* __restrict__ dst, int n4) {
    int i = blockIdx.x * blockDim.x + threadIdx.x;
    if (i >= n4) return;
    f32x4 v = *(const f32x4*)(src + (size_t)i * 4);
    u16x4 w;
    w.x = f2bf(v.x); w.y = f2bf(v.y); w.z = f2bf(v.z); w.w = f2bf(v.w);
    *(u16x4*)(dst + (size_t)i * 4) = w;
}

// ---------------- transpose f32 -> bf16: dst[j,k] = src[k,j] ----------------
__global__ __launch_bounds__(256) void transpose_bf16_kernel(
    const float* __restrict__ src, unsigned short* __restrict__ dst, int n) {
    __shared__ float lds[64][68];
    const int bx = blockIdx.x * 64;   // j base
    const int by = blockIdx.y * 64;   // k base
    const int t  = threadIdx.x;
    const int r  = t >> 2;            // 0..63
    const int c4 = (t & 3) * 16;      // 0/16/32/48
    const float* s = src + (size_t)(by + r) * n + bx + c4;
    #pragma unroll
    for (int i = 0; i < 4; ++i)
        *(f32x4*)&lds[r][c4 + i * 4] = *(const f32x4*)(s + i * 4);
    __syncthreads();
    unsigned short* d = dst + (size_t)(bx + r) * n + by + c4;
    #pragma unroll
    for (int i = 0; i < 4; ++i) {
        u16x4 w;
        w.x = f2bf(lds[c4 + i * 4 + 0][r]);
        w.y = f2bf(lds[c4 + i * 4 + 1][r]);
        w.z = f2bf(lds[c4 + i * 4 + 2][r]);
        w.w = f2bf(lds[c4 + i * 4 + 3][r]);
        *(u16x4*)(d + i * 4) = w;
    }
}

// ---------------- pack weights into 32x32x16-fragment-major layout ---------
// src (Nout x K row-major) -> dst: for each (strip=Nout/64, kt=K/64):
// 8 frags (fid = ks*2 + nblk, ks=kstep 0..3, nblk 0..1), 64 lanes x 16B:
//   lane l holds W[strip*64 + nblk*32 + (l&31)][kt*64 + ks*16 + (l>>5)*8 + e]
template <int SRC_F32>
__global__ __launch_bounds__(512) void pack_w_kernel(
    const void* __restrict__ src, unsigned short* __restrict__ dst, int K) {
    __shared__ unsigned short lds[64][72];   // row stride 144B (16B-aligned)
    const int nkt   = K >> 6;
    const int strip = blockIdx.x;
    const int kt    = blockIdx.y;
    const int t     = threadIdx.x;
    {
        const int r = t >> 3, c8 = (t & 7) * 8;
        if (SRC_F32) {
            const float* s = (const float*)src + (size_t)(strip * 64 + r) * K + kt * 64 + c8;
            f32x4 a = *(const f32x4*)s, b = *(const f32x4*)(s + 4);
            u16x4 w0, w1;
            w0.x = f2bf(a.x); w0.y = f2bf(a.y); w0.z = f2bf(a.z); w0.w = f2bf(a.w);
            w1.x = f2bf(b.x); w1.y = f2bf(b.y); w1.z = f2bf(b.z); w1.w = f2bf(b.w);
            *(u16x4*)&lds[r][c8] = w0; *(u16x4*)&lds[r][c8 + 4] = w1;
        } else {
            const unsigned short* s = (const unsigned short*)src + (size_t)(strip * 64 + r) * K + kt * 64 + c8;
            *(s16x8*)&lds[r][c8] = *(const s16x8*)s;
        }
    }
    __syncthreads();
    const int fid = t >> 6, lane = t & 63;
    const int nblk = fid & 1, ks = fid >> 1;
    const int lrow32 = lane & 31, khi = lane >> 5;
    s16x8 v = *(const s16x8*)&lds[nblk * 32 + lrow32][ks * 16 + khi * 8];
    size_t off = (((size_t)strip * nkt + kt) * 8 + fid) * 512 + lane * 8;
    *(s16x8*)&dst[off] = v;
}

// ---------------- b_comb = mlp_w @ out_proj_b + mlp_b (wave per row) -------
__global__ __launch_bounds__(256) void bcomb_kernel(
    const float* __restrict__ mlp_w, const float* __restrict__ opb,
    const float* __restrict__ mlpb, float* __restrict__ bcomb) {
    const int wave = threadIdx.x >> 6, lane = threadIdx.x & 63;
    const int row = blockIdx.x * 4 + wave;
    const float* r = mlp_w + (size_t)row * ED;
    float s = 0.0f;
    for (int k = lane * 4; k < ED; k += 256) {
        f32x4 a = *(const f32x4*)(r + k);
        f32x4 b = *(const f32x4*)(opb + k);
        s += a.x * b.x + a.y * b.y + a.z * b.z + a.w * b.w;
    }
    #pragma unroll
    for (int off = 32; off > 0; off >>= 1) s += __shfl_xor(s, off, 64);
    if (lane == 0) bcomb[row] = s + mlpb[row];
}

// ---------------- window partition: x -> tok (B,N,E) bf16 ----------------
__global__ void partition_kernel(const float* __restrict__ x,
                                 unsigned short* __restrict__ tok) {
    int idx = blockIdx.x * blockDim.x + threadIdx.x;
    int m = idx & 15;
    int t = idx >> 4;
    int Y = t & 63; t >>= 6;
    int X = t & 63; t >>= 6;
    int c = t & 31;
    int b = t >> 5;
    f32x4 xv = *(const f32x4*)(x + (size_t)idx * 4);
    int nx = X >> 2, px = X & 3;
    int ny = Y >> 2, py = Y & 3;
    int n = nx * 256 + ny * 16 + m;
    int e = c * 64 + px * 16 + py * 4;
    size_t dst = (size_t)(b * NTOK + n) * ED + e;
    u16x4 w;
    w.x = f2bf(xv.x); w.y = f2bf(xv.y); w.z = f2bf(xv.z); w.w = f2bf(xv.w);
    *(u16x4*)&tok[dst] = w;
}

// ---------------- 128x128 4-wave bf16 GEMM (for small W_comb job) ----------
__global__ __launch_bounds__(256) void gemm128(
    const unsigned short* __restrict__ A,   // M x K bf16
    const unsigned short* __restrict__ W,   // Nout x K bf16
    const float* __restrict__ bias,         // Nout f32
    unsigned short* __restrict__ C,         // M x Nout bf16
    int M, int Nout, int K)
{
    __shared__ unsigned short ldsA[128 * 64];
    __shared__ unsigned short ldsW[128 * 64];

    const int tid  = threadIdx.x;
    const int wave = tid >> 6;
    const int lane = tid & 63;
    const int bm = blockIdx.x * 128;
    const int bn = blockIdx.y * 128;
    const int wm = (wave >> 1) * 64;
    const int wn = (wave & 1) * 64;

    f32x4 acc[4][4] = {};

    const int srow = lane >> 3;
    const int scol = (lane & 7) * 8;
    const int lrow = lane & 15;
    const int lk   = (lane >> 4) * 8;

    const int nkt = K >> 6;
    for (int kt = 0; kt < nkt; ++kt) {
        const int kbase = kt * 64;
        #pragma unroll
        for (int q = 0; q < 4; ++q) {
            int chunk = wave * 4 + q;
            int row = chunk * 8 + srow;
            const unsigned short* ga = A + (size_t)(bm + row) * K + kbase + scol;
            const unsigned short* gw = W + (size_t)(bn + row) * K + kbase + scol;
            __builtin_amdgcn_global_load_lds(
                (const __attribute__((address_space(1))) void*)ga,
                (__attribute__((address_space(3))) void*)(&ldsA[chunk * 512]),
                16, 0, 0);
            __builtin_amdgcn_global_load_lds(
                (const __attribute__((address_space(1))) void*)gw,
                (__attribute__((address_space(3))) void*)(&ldsW[chunk * 512]),
                16, 0, 0);
        }
        __syncthreads();

        #pragma unroll
        for (int ks = 0; ks < 2; ++ks) {
            const int k0 = ks * 32 + lk;
            s16x8 af[4], bf[4];
            #pragma unroll
            for (int m = 0; m < 4; ++m)
                af[m] = *(const s16x8*)&ldsA[(wm + m * 16 + lrow) * 64 + k0];
            #pragma unroll
            for (int n = 0; n < 4; ++n)
                bf[n] = *(const s16x8*)&ldsW[(wn + n * 16 + lrow) * 64 + k0];
            #pragma unroll
            for (int m = 0; m < 4; ++m)
                #pragma unroll
                for (int n = 0; n < 4; ++n)
                    acc[m][n] = __builtin_amdgcn_mfma_f32_16x16x32_bf16(
                        af[m], bf[n], acc[m][n], 0, 0, 0);
        }
        __syncthreads();
    }

    const int col   = lane & 15;
    const int rbase = (lane >> 4) * 4;
    #pragma unroll
    for (int n = 0; n < 4; ++n) {
        int cc = bn + wn + n * 16 + col;
        float bv = bias[cc];
        #pragma unroll
        for (int m = 0; m < 4; ++m)
            #pragma unroll
            for (int r = 0; r < 4; ++r) {
                int rr = bm + wm + m * 16 + rbase + r;
                C[(size_t)rr * Nout + cc] = f2bf(acc[m][n][r] + bv);
            }
    }
}

// ---------------- 256x256 GEMM, 32x32x16 MFMA, B direct-from-global -------
// C[r,j] = sum_k A[r,k] * W[j,k] + bias[j].  M == 16384, Nout % 1024 == 0.
// 8 waves (2M x 4N), per-wave 128x64 = 4m x 2n blocks of 32x32.
// A frag (m,ks): lane l holds A[m*32+(l&31)][ks*16+(l>>5)*8+e] (b128 from
// swizzled LDS). B frag (ks,nblk) prepacked (pack_w_kernel). Per tile t:
// E1=loadBk0(t+1), E2=stA(t+2), E3=loadBk1(t+1); W1/W2=vmcnt(8) as in r9.
// C/D layout: col=lane&31, row=(reg&3)+8*(reg>>2)+4*(lane>>5).
// OUT_MODE: 1 = bf16 row-major; 2 = f32 window-reverse scatter.
template <int OUT_MODE>
__global__ __launch_bounds__(512, 2) void gemm256(
    const unsigned short* __restrict__ A,   // M x K bf16 row-major
    const unsigned short* __restrict__ Bp,  // packed weights
    const float* __restrict__ bias,         // Nout f32
    void* __restrict__ Cv,                  // out per OUT_MODE
    int M, int Nout, int K)
{
    __shared__ unsigned short ldsA[2][2][128 * 64];

    const int tid  = threadIdx.x;
    const int wave = tid >> 6;
    const int lane = tid & 63;

    // L2-locality mapping (bijective, gm=64): XCD x owns m-band x; 8m x 4n
    // macro-tiles of 32 blocks = the concurrent set per XCD.
    const int f   = blockIdx.x;
    const int xcd = f & 7;
    const int r_  = f >> 3;
    const int mac = r_ >> 5;
    const int w_  = r_ & 31;
    const int bm  = (xcd * 8 + (w_ & 7)) * 256;
    const int bn  = (mac * 4 + (w_ >> 3)) * 256;

    const int wi     = wave >> 2;        // 0/1: M half
    const int wj     = wave & 3;         // 0-3: N quarter
    const int lrow32 = lane & 31;
    const int khi    = lane >> 5;        // k-group 0/1

    f32x16 acc[4][2] = {};               // [m-block][n-block], 32x32 each

    const int nkt = K >> 6;
    const unsigned short* Bbase =
        Bp + ((size_t)((bn >> 6) + wj) * nkt) * 4096 + lane * 8;

    const int srl   = lane >> 3;                         // 0-7
    const int sslot = (((lane & 7) ^ srl) << 3);         // pre-swizzled src off

    auto stA = [&](int db, int half, int tt) {
        const unsigned short* gb = A + (size_t)(bm + half * 128) * K + tt * 64;
        unsigned short* lb = &ldsA[db][half][0];
        #pragma unroll
        for (int q = 0; q < 2; ++q) {
            const int r0 = wave * 16 + q * 8;
            const unsigned short* ga = gb + (size_t)(r0 + srl) * K + sslot;
            __builtin_amdgcn_global_load_lds(
                (const __attribute__((address_space(1))) void*)ga,
                (__attribute__((address_space(3))) void*)(lb + r0 * 64),
                16, 0, 0);
        }
    };

    // A-read address helper: frag (m, ks) -> elem offset in half-tile LDS
    // row = m*32 + lrow32; global slot = 2*ks + khi; stored slot ^= row&7
    int arow[4], asw[4];
    #pragma unroll
    for (int m = 0; m < 4; ++m) {
        arow[m] = (m * 32 + lrow32) * 64;
        asw[m]  = (m * 32 + lrow32) & 7;
    }

    s16x8 A0[8], A1[8], Bk0[4], Bk1[4];  // A[ks*4+m], B[ks*2+nb] per half

    // ---- prologue: A(0)->db0, A(1)->db1, B(0) both halves
    stA(0, 0, 0); stA(0, 1, 0);
    stA(1, 0, 1); stA(1, 1, 1);
    {
        const unsigned short* fb = Bbase;   // kt = 0
        #pragma unroll
        for (int j = 0; j < 4; ++j) Bk0[j] = *(const s16x8*)(fb + j * 512);
        #pragma unroll
        for (int j = 0; j < 4; ++j) Bk1[j] = *(const s16x8*)(fb + (4 + j) * 512);
    }
    VMCNT(0);
    BARRIER();

    for (int t = 0; t < nkt; ++t) {
        const int db = t & 1;
        const unsigned short* hA = &ldsA[db][wi][0];
        const unsigned short* fbn = Bbase + (size_t)(t + 1) * 4096;

        // A reads: kh0 (ks=0,1) then kh1 (ks=2,3), 8 b128 each
        #pragma unroll
        for (int ks = 0; ks < 2; ++ks)
            #pragma unroll
            for (int m = 0; m < 4; ++m)
                A0[ks * 4 + m] = *(const s16x8*)&hA[arow[m] + (((2 * ks + khi) ^ asw[m]) << 3)];
        #pragma unroll
        for (int ks = 0; ks < 2; ++ks)
            #pragma unroll
            for (int m = 0; m < 4; ++m)
                A1[ks * 4 + m] = *(const s16x8*)&hA[arow[m] + (((2 * (ks + 2) + khi) ^ asw[m]) << 3)];

        // W1: Bk0(t) resident
        if (t + 2 < nkt) { VMCNT(8); } else { VMCNT(0); }
        LGKM8();   // A0 resident (oldest 8 of 16 ds_reads)
        __builtin_amdgcn_s_setprio(1);
        #pragma unroll
        for (int ks = 0; ks < 2; ++ks)
            #pragma unroll
            for (int m = 0; m < 4; ++m)
                #pragma unroll
                for (int nb = 0; nb < 2; ++nb)
                    acc[m][nb] = __builtin_amdgcn_mfma_f32_32x32x16_bf16(
                        A0[ks * 4 + m], Bk0[ks * 2 + nb], acc[m][nb], 0, 0, 0);
        __builtin_amdgcn_s_setprio(0);

        // E1: next-tile Bk0 (WAR on Bk0 regs keeps this after the MFMAs)
        if (t + 1 < nkt) {
            #pragma unroll
            for (int j = 0; j < 4; ++j) Bk0[j] = *(const s16x8*)(fbn + j * 512);
        }

        LGKM0();   // A1 resident (drained under kh0 MFMAs)
        BARRIER(); // #1: all waves done reading db

        // E2: stage A(t+2) -> db
        if (t + 2 < nkt) { stA(db, 0, t + 2); stA(db, 1, t + 2); }

        // W2: Bk1(t) + stA(t+1) resident
        if (t + 2 < nkt) { VMCNT(8); } else { VMCNT(0); }
        __builtin_amdgcn_s_setprio(1);
        #pragma unroll
        for (int ks = 0; ks < 2; ++ks)
            #pragma unroll
            for (int m = 0; m < 4; ++m)
                #pragma unroll
                for (int nb = 0; nb < 2; ++nb)
                    acc[m][nb] = __builtin_amdgcn_mfma_f32_32x32x16_bf16(
                        A1[ks * 4 + m], Bk1[ks * 2 + nb], acc[m][nb], 0, 0, 0);
        __builtin_amdgcn_s_setprio(0);

        // E3: next-tile Bk1
        if (t + 1 < nkt) {
            #pragma unroll
            for (int j = 0; j < 4; ++j) Bk1[j] = *(const s16x8*)(fbn + (4 + j) * 512);
        }
        BARRIER(); // #2: tile t+1 A resident everywhere (drained at W2)
    }

    // ---- epilogue: C/D col=lane&31, row=(reg&3)+8*(reg>>2)+4*(lane>>5)
    const int rowbase = bm + wi * 128;
    float bv[2];
    #pragma unroll
    for (int nb = 0; nb < 2; ++nb)
        bv[nb] = bias[bn + wj * 64 + nb * 32 + lrow32];

    if (OUT_MODE == 1) {
        unsigned short* C = (unsigned short*)Cv;
        #pragma unroll
        for (int m = 0; m < 4; ++m) {
            #pragma unroll
            for (int nb = 0; nb < 2; ++nb) {
                const int cc = bn + wj * 64 + nb * 32 + lrow32;
                #pragma unroll
                for (int rg = 0; rg < 4; ++rg) {
                    const int r0 = rowbase + m * 32 + rg * 8 + 4 * khi;
                    #pragma unroll
                    for (int j = 0; j < 4; ++j)
                        C[(size_t)(r0 + j) * Nout + cc] = f2bf(acc[m][nb][rg * 4 + j] + bv[nb]);
                }
            }
        }
    } else {
        // window-reverse scatter: rr=(b,nx,ny,nz), cc=(c,px,py,pz) ->
        // out[b,c, px*16+nx, py*16+ny, pz*16+nz]; 4 consecutive regs = nz run
        float* outp = (float*)Cv;
        #pragma unroll
        for (int nb = 0; nb < 2; ++nb) {
            const int cc = bn + wj * 64 + nb * 32 + lrow32;
            const int c  = cc >> 6, px = (cc >> 4) & 3,
                      py = (cc >> 2) & 3, pz = cc & 3;
            #pragma unroll
            for (int m = 0; m < 4; ++m) {
                #pragma unroll
                for (int rg = 0; rg < 4; ++rg) {
                    const int rr0 = rowbase + m * 32 + rg * 8 + 4 * khi;
                    const int b   = rr0 >> 12, nx = (rr0 >> 8) & 15,
                              ny  = (rr0 >> 4) & 15, nz0 = rr0 & 15;
                    float* dst = outp
                        + ((size_t)((b * NC + c) * 64 + px * 16 + nx)) * 4096
                        + (size_t)(py * 16 + ny) * 64 + pz * 16 + nz0;
                    f32x4 w = {acc[m][nb][rg * 4 + 0] + bv[nb],
                               acc[m][nb][rg * 4 + 1] + bv[nb],
                               acc[m][nb][rg * 4 + 2] + bv[nb],
                               acc[m][nb][rg * 4 + 3] + bv[nb]};
                    *(f32x4*)dst = w;
                }
            }
        }
    }
}

// ---------------- attention over B axis: seq=4, batch = N*H ----------------
// block = token n (4096 blocks, 512 thr); wave handles 2 heads; u16x4 loads.
__global__ __launch_bounds__(512) void attn_kernel(
    const unsigned short* __restrict__ qkv, unsigned short* __restrict__ o)
{
    const int n    = blockIdx.x;
    const int wave = threadIdx.x >> 6;
    const int lane = threadIdx.x & 63;
    const int h    = wave * 2 + (lane >> 5);
    const int dl   = (lane & 31) * 4;
    const float scale = 0.0883883476483184405501f;  // 1/sqrt(128)

    float q[4][4], k[4][4], v[4][4];
    #pragma unroll
    for (int b = 0; b < 4; ++b) {
        size_t base = (size_t)(b * NTOK + n) * (3 * ED) + h * HD + dl;
        u16x4 uq = *(const u16x4*)&qkv[base];
        u16x4 uk = *(const u16x4*)&qkv[base + ED];
        u16x4 uv = *(const u16x4*)&qkv[base + 2 * ED];
        #pragma unroll
        for (int i = 0; i < 4; ++i) {
            q[b][i] = bf2f(uq[i]); k[b][i] = bf2f(uk[i]); v[b][i] = bf2f(uv[i]);
        }
    }

    float sc[4][4];
    #pragma unroll
    for (int s = 0; s < 4; ++s) {
        #pragma unroll
        for (int t = 0; t < 4; ++t) {
            float p = q[s][0] * k[t][0] + q[s][1] * k[t][1]
                    + q[s][2] * k[t][2] + q[s][3] * k[t][3];
            #pragma unroll
            for (int off = 16; off > 0; off >>= 1)   // reduce within 32-group
                p += __shfl_xor(p, off, 64);
            sc[s][t] = p * scale;
        }
    }

    #pragma unroll
    for (int s = 0; s < 4; ++s) {
        float mx = fmaxf(fmaxf(sc[s][0], sc[s][1]), fmaxf(sc[s][2], sc[s][3]));
        float e0 = __expf(sc[s][0] - mx);
        float e1 = __expf(sc[s][1] - mx);
        float e2 = __expf(sc[s][2] - mx);
        float e3 = __expf(sc[s][3] - mx);
        float inv = 1.0f / (e0 + e1 + e2 + e3);
        u16x4 ov;
        #pragma unroll
        for (int i = 0; i < 4; ++i) {
            float oo = (e0 * v[0][i] + e1 * v[1][i] + e2 * v[2][i] + e3 * v[3][i]) * inv;
            ov[i] = f2bf(oo);
        }
        *(u16x4*)&o[(size_t)(s * NTOK + n) * ED + h * HD + dl] = ov;
    }
}

// ---------------------------------------------------------------------------
extern "C" void kernel_launch(void* const* d_in, const int* in_sizes, int n_in,
                              void* d_out, int out_size, void* d_ws, size_t ws_size,
                              hipStream_t stream) {
    const float* x          = (const float*)d_in[0];
    const float* in_proj_w  = (const float*)d_in[1];
    const float* in_proj_b  = (const float*)d_in[2];
    const float* out_proj_w = (const float*)d_in[3];
    const float* out_proj_b = (const float*)d_in[4];
    const float* mlp_w      = (const float*)d_in[5];
    const float* mlp_b      = (const float*)d_in[6];
    float* out = (float*)d_out;

    const size_t M = 16384;                       // B*N rows
    char* ws = (char*)d_ws;
    size_t off = 0;
    unsigned short* tok     = (unsigned short*)(ws + off); off += M * ED * 2;
    unsigned short* w_inP   = (unsigned short*)(ws + off); off += (size_t)3 * ED * ED * 2;
    unsigned short* w_mlp   = (unsigned short*)(ws + off); off += (size_t)ED * ED * 2;
    unsigned short* w_outT  = (unsigned short*)(ws + off); off += (size_t)ED * ED * 2;
    unsigned short* w_comb  = (unsigned short*)(ws + off); off += (size_t)ED * ED * 2;
    unsigned short* w_combP = (unsigned short*)(ws + off); off += (size_t)ED * ED * 2;
    float* zbias            = (float*)(ws + off);          off += ED * 4;
    float* b_comb           = (float*)(ws + off);          off += ED * 4;
    unsigned short* obuf    = (unsigned short*)(ws + off); off += M * ED * 2;
    unsigned short* qkv     = (unsigned short*)(ws + off); off += M * 3 * ED * 2;

    if (ws_size < off) {
        fprintf(stderr, "kernel_launch: ws too small (%zu < %zu)\n", ws_size, off);
        return;
    }

    // weight prep: pack in_proj (fused f32->bf16), convert mlp, transpose out
    pack_w_kernel<1><<<dim3(3 * ED / 64, ED / 64), 512, 0, stream>>>(
        in_proj_w, w_inP, ED);
    {
        int n4 = ED * ED / 4;
        f32_to_bf16_kernel<<<(n4 + 255) / 256, 256, 0, stream>>>(mlp_w, w_mlp, n4);
        transpose_bf16_kernel<<<dim3(ED / 64, ED / 64), 256, 0, stream>>>(
            out_proj_w, w_outT, ED);
        hipMemsetAsync(zbias, 0, ED * sizeof(float), stream);
    }

    // W_comb = mlp_w @ out_proj_w  (row-major [j][k]); then pack
    gemm128<<<dim3(ED / 128, ED / 128), 256, 0, stream>>>(
        w_mlp, w_outT, zbias, w_comb, ED, ED, ED);
    pack_w_kernel<0><<<dim3(ED / 64, ED / 64), 512, 0, stream>>>(
        w_comb, w_combP, ED);
    // b_comb = mlp_w @ out_proj_b + mlp_b
    bcomb_kernel<<<ED / 4, 256, 0, stream>>>(mlp_w, out_proj_b, mlp_b, b_comb);

    // window partition
    partition_kernel<<<(NB * NC * 64 * 64 * 16) / 256, 256, 0, stream>>>(x, tok);

    // qkv = tok @ in_proj_w^T + in_proj_b   (16384 x 6144 x 2048)
    gemm256<1><<<dim3(64 * (6144 / 256)), 512, 0, stream>>>(
        tok, w_inP, in_proj_b, qkv, 16384, 6144, 2048);

    // attention (seq=B=4, batch=N*H)
    attn_kernel<<<NTOK, 512, 0, stream>>>(qkv, obuf);

    // out = reverse(obuf @ W_comb^T + b_comb)  -- scatter epilogue
    gemm256<2><<<dim3(64 * (2048 / 256)), 512, 0, stream>>>(
        obuf, w_combP, b_comb, out, 16384, 2048, 2048);
}

// Round 14
// 745.375 us; speedup vs baseline: 1.0016x; 1.0001x over previous
//
#include <hip/hip_runtime.h>
#include <stdio.h>

// ---------------------------------------------------------------------------
// WindowAttention: partition -> QKV gemm -> attention over B axis ->
// fused (out_proj @ mlp) gemm with window-reverse scatter epilogue.
// GEMM: 256x256, v_mfma_f32_32x32x16_bf16 (higher ceiling, half the MFMA
// instruction count vs 16x16x32); A staged via LDS (swizzled global_load_lds),
// B direct-from-global in fragment-prepacked layout. r9 staging skeleton.
// ---------------------------------------------------------------------------

typedef __attribute__((ext_vector_type(4))) float f32x4;
typedef __attribute__((ext_vector_type(16))) float f32x16;
typedef __attribute__((ext_vector_type(8))) short s16x8;
typedef __attribute__((ext_vector_type(2))) unsigned short u16x2;
typedef __attribute__((ext_vector_type(4))) unsigned short u16x4;

#define NB 4        // batch B (attention seq len)
#define NC 32       // channels
#define NTOK 4096   // N = 16^3 windows
#define ED 2048     // embed dim E
#define NH 16       // heads
#define HD 128      // head dim

__device__ __forceinline__ unsigned short f2bf(float f) {
    union { float f; unsigned int u; } v; v.f = f;
    unsigned int r = (v.u + 0x7fffu + ((v.u >> 16) & 1u)) >> 16;
    return (unsigned short)r;
}
__device__ __forceinline__ float bf2f(unsigned short u) {
    union { unsigned int u; float f; } v; v.u = ((unsigned int)u) << 16;
    return v.f;
}

#define BARRIER() asm volatile("s_barrier" ::: "memory")
#define LGKM0() do { asm volatile("s_waitcnt lgkmcnt(0)" ::: "memory"); \
                     __builtin_amdgcn_sched_barrier(0); } while (0)
#define LGKM8() do { asm volatile("s_waitcnt lgkmcnt(8)" ::: "memory"); \
                     __builtin_amdgcn_sched_barrier(0); } while (0)
#define VMCNT(n) asm volatile("s_waitcnt vmcnt(" #n ")" ::: "memory")

// ---------------- fp32 -> bf16 convert (weights) ----------------
__global__ void f32_to_bf16_kernel(const float* __restrict__ src,
                                   unsigned short* __restrict__ dst, int n4) {
    int i = blockIdx.x * blockDim.x + threadIdx.x;
    if (i >= n4) return;
    f32x4 v = *(const f32x4*)(src + (size_t)i * 4);
    u16x4 w;
    w.x = f2bf(v.x); w.y = f2bf(v.y); w.z = f2bf(v.z); w.w = f2bf(v.w);
    *(u16x4*)(dst + (size_t)i * 4) = w;
}

// ---------------- transpose f32 -> bf16: dst[j,k] = src[k,j] ----------------
__global__ __launch_bounds__(256) void transpose_bf16_kernel(
    const float* __restrict__ src, unsigned short* __restrict__ dst, int n) {
    __shared__ float lds[64][68];
    const int bx = blockIdx.x * 64;   // j base
    const int by = blockIdx.y * 64;   // k base
    const int t  = threadIdx.x;
    const int r  = t >> 2;            // 0..63
    const int c4 = (t & 3) * 16;      // 0/16/32/48
    const float* s = src + (size_t)(by + r) * n + bx + c4;
    #pragma unroll
    for (int i = 0; i < 4; ++i)
        *(f32x4*)&lds[r][c4 + i * 4] = *(const f32x4*)(s + i * 4);
    __syncthreads();
    unsigned short* d = dst + (size_t)(bx + r) * n + by + c4;
    #pragma unroll
    for (int i = 0; i < 4; ++i) {
        u16x4 w;
        w.x = f2bf(lds[c4 + i * 4 + 0][r]);
        w.y = f2bf(lds[c4 + i * 4 + 1][r]);
        w.z = f2bf(lds[c4 + i * 4 + 2][r]);
        w.w = f2bf(lds[c4 + i * 4 + 3][r]);
        *(u16x4*)(d + i * 4) = w;
    }
}

// ---------------- pack weights into 32x32x16-fragment-major layout ---------
// src (Nout x K row-major) -> dst: for each (strip=Nout/64, kt=K/64):
// 8 frags (fid = ks*2 + nblk, ks=kstep 0..3, nblk 0..1), 64 lanes x 16B:
//   lane l holds W[strip*64 + nblk*32 + (l&31)][kt*64 + ks*16 + (l>>5)*8 + e]
template <int SRC_F32>
__global__ __launch_bounds__(512) void pack_w_kernel(
    const void* __restrict__ src, unsigned short* __restrict__ dst, int K) {
    __shared__ unsigned short lds[64][72];   // row stride 144B (16B-aligned)
    const int nkt   = K >> 6;
    const int strip = blockIdx.x;
    const int kt    = blockIdx.y;
    const int t     = threadIdx.x;
    {
        const int r = t >> 3, c8 = (t & 7) * 8;
        if (SRC_F32) {
            const float* s = (const float*)src + (size_t)(strip * 64 + r) * K + kt * 64 + c8;
            f32x4 a = *(const f32x4*)s, b = *(const f32x4*)(s + 4);
            u16x4 w0, w1;
            w0.x = f2bf(a.x); w0.y = f2bf(a.y); w0.z = f2bf(a.z); w0.w = f2bf(a.w);
            w1.x = f2bf(b.x); w1.y = f2bf(b.y); w1.z = f2bf(b.z); w1.w = f2bf(b.w);
            *(u16x4*)&lds[r][c8] = w0; *(u16x4*)&lds[r][c8 + 4] = w1;
        } else {
            const unsigned short* s = (const unsigned short*)src + (size_t)(strip * 64 + r) * K + kt * 64 + c8;
            *(s16x8*)&lds[r][c8] = *(const s16x8*)s;
        }
    }
    __syncthreads();
    const int fid = t >> 6, lane = t & 63;
    const int nblk = fid & 1, ks = fid >> 1;
    const int lrow32 = lane & 31, khi = lane >> 5;
    s16x8 v = *(const s16x8*)&lds[nblk * 32 + lrow32][ks * 16 + khi * 8];
    size_t off = (((size_t)strip * nkt + kt) * 8 + fid) * 512 + lane * 8;
    *(s16x8*)&dst[off] = v;
}

// ---------------- b_comb = mlp_w @ out_proj_b + mlp_b (wave per row) -------
__global__ __launch_bounds__(256) void bcomb_kernel(
    const float* __restrict__ mlp_w, const float* __restrict__ opb,
    const float* __restrict__ mlpb, float* __restrict__ bcomb) {
    const int wave = threadIdx.x >> 6, lane = threadIdx.x & 63;
    const int row = blockIdx.x * 4 + wave;
    const float* r = mlp_w + (size_t)row * ED;
    float s = 0.0f;
    for (int k = lane * 4; k < ED; k += 256) {
        f32x4 a = *(const f32x4*)(r + k);
        f32x4 b = *(const f32x4*)(opb + k);
        s += a.x * b.x + a.y * b.y + a.z * b.z + a.w * b.w;
    }
    #pragma unroll
    for (int off = 32; off > 0; off >>= 1) s += __shfl_xor(s, off, 64);
    if (lane == 0) bcomb[row] = s + mlpb[row];
}

// ---------------- window partition: x -> tok (B,N,E) bf16 ----------------
__global__ void partition_kernel(const float* __restrict__ x,
                                 unsigned short* __restrict__ tok) {
    int idx = blockIdx.x * blockDim.x + threadIdx.x;
    int m = idx & 15;
    int t = idx >> 4;
    int Y = t & 63; t >>= 6;
    int X = t & 63; t >>= 6;
    int c = t & 31;
    int b = t >> 5;
    f32x4 xv = *(const f32x4*)(x + (size_t)idx * 4);
    int nx = X >> 2, px = X & 3;
    int ny = Y >> 2, py = Y & 3;
    int n = nx * 256 + ny * 16 + m;
    int e = c * 64 + px * 16 + py * 4;
    size_t dst = (size_t)(b * NTOK + n) * ED + e;
    u16x4 w;
    w.x = f2bf(xv.x); w.y = f2bf(xv.y); w.z = f2bf(xv.z); w.w = f2bf(xv.w);
    *(u16x4*)&tok[dst] = w;
}

// ---------------- 128x128 4-wave bf16 GEMM (for small W_comb job) ----------
__global__ __launch_bounds__(256) void gemm128(
    const unsigned short* __restrict__ A,   // M x K bf16
    const unsigned short* __restrict__ W,   // Nout x K bf16
    const float* __restrict__ bias,         // Nout f32
    unsigned short* __restrict__ C,         // M x Nout bf16
    int M, int Nout, int K)
{
    __shared__ unsigned short ldsA[128 * 64];
    __shared__ unsigned short ldsW[128 * 64];

    const int tid  = threadIdx.x;
    const int wave = tid >> 6;
    const int lane = tid & 63;
    const int bm = blockIdx.x * 128;
    const int bn = blockIdx.y * 128;
    const int wm = (wave >> 1) * 64;
    const int wn = (wave & 1) * 64;

    f32x4 acc[4][4] = {};

    const int srow = lane >> 3;
    const int scol = (lane & 7) * 8;
    const int lrow = lane & 15;
    const int lk   = (lane >> 4) * 8;

    const int nkt = K >> 6;
    for (int kt = 0; kt < nkt; ++kt) {
        const int kbase = kt * 64;
        #pragma unroll
        for (int q = 0; q < 4; ++q) {
            int chunk = wave * 4 + q;
            int row = chunk * 8 + srow;
            const unsigned short* ga = A + (size_t)(bm + row) * K + kbase + scol;
            const unsigned short* gw = W + (size_t)(bn + row) * K + kbase + scol;
            __builtin_amdgcn_global_load_lds(
                (const __attribute__((address_space(1))) void*)ga,
                (__attribute__((address_space(3))) void*)(&ldsA[chunk * 512]),
                16, 0, 0);
            __builtin_amdgcn_global_load_lds(
                (const __attribute__((address_space(1))) void*)gw,
                (__attribute__((address_space(3))) void*)(&ldsW[chunk * 512]),
                16, 0, 0);
        }
        __syncthreads();

        #pragma unroll
        for (int ks = 0; ks < 2; ++ks) {
            const int k0 = ks * 32 + lk;
            s16x8 af[4], bf[4];
            #pragma unroll
            for (int m = 0; m < 4; ++m)
                af[m] = *(const s16x8*)&ldsA[(wm + m * 16 + lrow) * 64 + k0];
            #pragma unroll
            for (int n = 0; n < 4; ++n)
                bf[n] = *(const s16x8*)&ldsW[(wn + n * 16 + lrow) * 64 + k0];
            #pragma unroll
            for (int m = 0; m < 4; ++m)
                #pragma unroll
                for (int n = 0; n < 4; ++n)
                    acc[m][n] = __builtin_amdgcn_mfma_f32_16x16x32_bf16(
                        af[m], bf[n], acc[m][n], 0, 0, 0);
        }
        __syncthreads();
    }

    const int col   = lane & 15;
    const int rbase = (lane >> 4) * 4;
    #pragma unroll
    for (int n = 0; n < 4; ++n) {
        int cc = bn + wn + n * 16 + col;
        float bv = bias[cc];
        #pragma unroll
        for (int m = 0; m < 4; ++m)
            #pragma unroll
            for (int r = 0; r < 4; ++r) {
                int rr = bm + wm + m * 16 + rbase + r;
                C[(size_t)rr * Nout + cc] = f2bf(acc[m][n][r] + bv);
            }
    }
}

// ---------------- 256x256 GEMM, 32x32x16 MFMA, B direct-from-global -------
// C[r,j] = sum_k A[r,k] * W[j,k] + bias[j].  M == 16384, Nout % 1024 == 0.
// 8 waves (2M x 4N), per-wave 128x64 = 4m x 2n blocks of 32x32.
// A frag (m,ks): lane l holds A[m*32+(l&31)][ks*16+(l>>5)*8+e] (b128 from
// swizzled LDS). B frag (ks,nblk) prepacked (pack_w_kernel). Per tile t:
// E1=loadBk0(t+1), E2=stA(t+2), E3=loadBk1(t+1); W1/W2=vmcnt(8) as in r9.
// C/D layout: col=lane&31, row=(reg&3)+8*(reg>>2)+4*(lane>>5).
// OUT_MODE: 1 = bf16 row-major; 2 = f32 window-reverse scatter.
template <int OUT_MODE>
__global__ __launch_bounds__(512, 2) void gemm256(
    const unsigned short* __restrict__ A,   // M x K bf16 row-major
    const unsigned short* __restrict__ Bp,  // packed weights
    const float* __restrict__ bias,         // Nout f32
    void* __restrict__ Cv,                  // out per OUT_MODE
    int M, int Nout, int K)
{
    __shared__ unsigned short ldsA[2][2][128 * 64];

    const int tid  = threadIdx.x;
    const int wave = tid >> 6;
    const int lane = tid & 63;

    // L2-locality mapping (bijective, gm=64): XCD x owns m-band x; 8m x 4n
    // macro-tiles of 32 blocks = the concurrent set per XCD.
    const int f   = blockIdx.x;
    const int xcd = f & 7;
    const int r_  = f >> 3;
    const int mac = r_ >> 5;
    const int w_  = r_ & 31;
    const int bm  = (xcd * 8 + (w_ & 7)) * 256;
    const int bn  = (mac * 4 + (w_ >> 3)) * 256;

    const int wi     = wave >> 2;        // 0/1: M half
    const int wj     = wave & 3;         // 0-3: N quarter
    const int lrow32 = lane & 31;
    const int khi    = lane >> 5;        // k-group 0/1

    f32x16 acc[4][2] = {};               // [m-block][n-block], 32x32 each

    const int nkt = K >> 6;
    const unsigned short* Bbase =
        Bp + ((size_t)((bn >> 6) + wj) * nkt) * 4096 + lane * 8;

    const int srl   = lane >> 3;                         // 0-7
    const int sslot = (((lane & 7) ^ srl) << 3);         // pre-swizzled src off

    auto stA = [&](int db, int half, int tt) {
        const unsigned short* gb = A + (size_t)(bm + half * 128) * K + tt * 64;
        unsigned short* lb = &ldsA[db][half][0];
        #pragma unroll
        for (int q = 0; q < 2; ++q) {
            const int r0 = wave * 16 + q * 8;
            const unsigned short* ga = gb + (size_t)(r0 + srl) * K + sslot;
            __builtin_amdgcn_global_load_lds(
                (const __attribute__((address_space(1))) void*)ga,
                (__attribute__((address_space(3))) void*)(lb + r0 * 64),
                16, 0, 0);
        }
    };

    // A-read address helper: frag (m, ks) -> elem offset in half-tile LDS
    // row = m*32 + lrow32; global slot = 2*ks + khi; stored slot ^= row&7
    int arow[4], asw[4];
    #pragma unroll
    for (int m = 0; m < 4; ++m) {
        arow[m] = (m * 32 + lrow32) * 64;
        asw[m]  = (m * 32 + lrow32) & 7;
    }

    s16x8 A0[8], A1[8], Bk0[4], Bk1[4];  // A[ks*4+m], B[ks*2+nb] per half

    // ---- prologue: A(0)->db0, A(1)->db1, B(0) both halves
    stA(0, 0, 0); stA(0, 1, 0);
    stA(1, 0, 1); stA(1, 1, 1);
    {
        const unsigned short* fb = Bbase;   // kt = 0
        #pragma unroll
        for (int j = 0; j < 4; ++j) Bk0[j] = *(const s16x8*)(fb + j * 512);
        #pragma unroll
        for (int j = 0; j < 4; ++j) Bk1[j] = *(const s16x8*)(fb + (4 + j) * 512);
    }
    VMCNT(0);
    BARRIER();

    for (int t = 0; t < nkt; ++t) {
        const int db = t & 1;
        const unsigned short* hA = &ldsA[db][wi][0];
        const unsigned short* fbn = Bbase + (size_t)(t + 1) * 4096;

        // A reads: kh0 (ks=0,1) then kh1 (ks=2,3), 8 b128 each
        #pragma unroll
        for (int ks = 0; ks < 2; ++ks)
            #pragma unroll
            for (int m = 0; m < 4; ++m)
                A0[ks * 4 + m] = *(const s16x8*)&hA[arow[m] + (((2 * ks + khi) ^ asw[m]) << 3)];
        #pragma unroll
        for (int ks = 0; ks < 2; ++ks)
            #pragma unroll
            for (int m = 0; m < 4; ++m)
                A1[ks * 4 + m] = *(const s16x8*)&hA[arow[m] + (((2 * (ks + 2) + khi) ^ asw[m]) << 3)];

        // W1: Bk0(t) resident
        if (t + 2 < nkt) { VMCNT(8); } else { VMCNT(0); }
        LGKM8();   // A0 resident (oldest 8 of 16 ds_reads)
        __builtin_amdgcn_s_setprio(1);
        #pragma unroll
        for (int ks = 0; ks < 2; ++ks)
            #pragma unroll
            for (int m = 0; m < 4; ++m)
                #pragma unroll
                for (int nb = 0; nb < 2; ++nb)
                    acc[m][nb] = __builtin_amdgcn_mfma_f32_32x32x16_bf16(
                        A0[ks * 4 + m], Bk0[ks * 2 + nb], acc[m][nb], 0, 0, 0);
        __builtin_amdgcn_s_setprio(0);

        // E1: next-tile Bk0 (WAR on Bk0 regs keeps this after the MFMAs)
        if (t + 1 < nkt) {
            #pragma unroll
            for (int j = 0; j < 4; ++j) Bk0[j] = *(const s16x8*)(fbn + j * 512);
        }

        LGKM0();   // A1 resident (drained under kh0 MFMAs)
        BARRIER(); // #1: all waves done reading db

        // E2: stage A(t+2) -> db
        if (t + 2 < nkt) { stA(db, 0, t + 2); stA(db, 1, t + 2); }

        // W2: Bk1(t) + stA(t+1) resident
        if (t + 2 < nkt) { VMCNT(8); } else { VMCNT(0); }
        __builtin_amdgcn_s_setprio(1);
        #pragma unroll
        for (int ks = 0; ks < 2; ++ks)
            #pragma unroll
            for (int m = 0; m < 4; ++m)
                #pragma unroll
                for (int nb = 0; nb < 2; ++nb)
                    acc[m][nb] = __builtin_amdgcn_mfma_f32_32x32x16_bf16(
                        A1[ks * 4 + m], Bk1[ks * 2 + nb], acc[m][nb], 0, 0, 0);
        __builtin_amdgcn_s_setprio(0);

        // E3: next-tile Bk1
        if (t + 1 < nkt) {
            #pragma unroll
            for (int j = 0; j < 4; ++j) Bk1[j] = *(const s16x8*)(fbn + (4 + j) * 512);
        }
        BARRIER(); // #2: tile t+1 A resident everywhere (drained at W2)
    }

    // ---- epilogue: C/D col=lane&31, row=(reg&3)+8*(reg>>2)+4*(lane>>5)
    const int rowbase = bm + wi * 128;
    float bv[2];
    #pragma unroll
    for (int nb = 0; nb < 2; ++nb)
        bv[nb] = bias[bn + wj * 64 + nb * 32 + lrow32];

    if (OUT_MODE == 1) {
        unsigned short* C = (unsigned short*)Cv;
        #pragma unroll
        for (int m = 0; m < 4; ++m) {
            #pragma unroll
            for (int nb = 0; nb < 2; ++nb) {
                const int cc = bn + wj * 64 + nb * 32 + lrow32;
                #pragma unroll
                for (int rg = 0; rg < 4; ++rg) {
                    const int r0 = rowbase + m * 32 + rg * 8 + 4 * khi;
                    #pragma unroll
                    for (int j = 0; j < 4; ++j)
                        C[(size_t)(r0 + j) * Nout + cc] = f2bf(acc[m][nb][rg * 4 + j] + bv[nb]);
                }
            }
        }
    } else {
        // window-reverse scatter: rr=(b,nx,ny,nz), cc=(c,px,py,pz) ->
        // out[b,c, px*16+nx, py*16+ny, pz*16+nz]; 4 consecutive regs = nz run
        float* outp = (float*)Cv;
        #pragma unroll
        for (int nb = 0; nb < 2; ++nb) {
            const int cc = bn + wj * 64 + nb * 32 + lrow32;
            const int c  = cc >> 6, px = (cc >> 4) & 3,
                      py = (cc >> 2) & 3, pz = cc & 3;
            #pragma unroll
            for (int m = 0; m < 4; ++m) {
                #pragma unroll
                for (int rg = 0; rg < 4; ++rg) {
                    const int rr0 = rowbase + m * 32 + rg * 8 + 4 * khi;
                    const int b   = rr0 >> 12, nx = (rr0 >> 8) & 15,
                              ny  = (rr0 >> 4) & 15, nz0 = rr0 & 15;
                    float* dst = outp
                        + ((size_t)((b * NC + c) * 64 + px * 16 + nx)) * 4096
                        + (size_t)(py * 16 + ny) * 64 + pz * 16 + nz0;
                    f32x4 w = {acc[m][nb][rg * 4 + 0] + bv[nb],
                               acc[m][nb][rg * 4 + 1] + bv[nb],
                               acc[m][nb][rg * 4 + 2] + bv[nb],
                               acc[m][nb][rg * 4 + 3] + bv[nb]};
                    *(f32x4*)dst = w;
                }
            }
        }
    }
}

// ---------------- attention over B axis: seq=4, batch = N*H ----------------
// block = token n (4096 blocks, 512 thr); wave handles 2 heads; u16x4 loads.
__global__ __launch_bounds__(512) void attn_kernel(
    const unsigned short* __restrict__ qkv, unsigned short* __restrict__ o)
{
    const int n    = blockIdx.x;
    const int wave = threadIdx.x >> 6;
    const int lane = threadIdx.x & 63;
    const int h    = wave * 2 + (lane >> 5);
    const int dl   = (lane & 31) * 4;
    const float scale = 0.0883883476483184405501f;  // 1/sqrt(128)

    float q[4][4], k[4][4], v[4][4];
    #pragma unroll
    for (int b = 0; b < 4; ++b) {
        size_t base = (size_t)(b * NTOK + n) * (3 * ED) + h * HD + dl;
        u16x4 uq = *(const u16x4*)&qkv[base];
        u16x4 uk = *(const u16x4*)&qkv[base + ED];
        u16x4 uv = *(const u16x4*)&qkv[base + 2 * ED];
        #pragma unroll
        for (int i = 0; i < 4; ++i) {
            q[b][i] = bf2f(uq[i]); k[b][i] = bf2f(uk[i]); v[b][i] = bf2f(uv[i]);
        }
    }

    float sc[4][4];
    #pragma unroll
    for (int s = 0; s < 4; ++s) {
        #pragma unroll
        for (int t = 0; t < 4; ++t) {
            float p = q[s][0] * k[t][0] + q[s][1] * k[t][1]
                    + q[s][2] * k[t][2] + q[s][3] * k[t][3];
            #pragma unroll
            for (int off = 16; off > 0; off >>= 1)   // reduce within 32-group
                p += __shfl_xor(p, off, 64);
            sc[s][t] = p * scale;
        }
    }

    #pragma unroll
    for (int s = 0; s < 4; ++s) {
        float mx = fmaxf(fmaxf(sc[s][0], sc[s][1]), fmaxf(sc[s][2], sc[s][3]));
        float e0 = __expf(sc[s][0] - mx);
        float e1 = __expf(sc[s][1] - mx);
        float e2 = __expf(sc[s][2] - mx);
        float e3 = __expf(sc[s][3] - mx);
        float inv = 1.0f / (e0 + e1 + e2 + e3);
        u16x4 ov;
        #pragma unroll
        for (int i = 0; i < 4; ++i) {
            float oo = (e0 * v[0][i] + e1 * v[1][i] + e2 * v[2][i] + e3 * v[3][i]) * inv;
            ov[i] = f2bf(oo);
        }
        *(u16x4*)&o[(size_t)(s * NTOK + n) * ED + h * HD + dl] = ov;
    }
}

// ---------------------------------------------------------------------------
extern "C" void kernel_launch(void* const* d_in, const int* in_sizes, int n_in,
                              void* d_out, int out_size, void* d_ws, size_t ws_size,
                              hipStream_t stream) {
    const float* x          = (const float*)d_in[0];
    const float* in_proj_w  = (const float*)d_in[1];
    const float* in_proj_b  = (const float*)d_in[2];
    const float* out_proj_w = (const float*)d_in[3];
    const float* out_proj_b = (const float*)d_in[4];
    const float* mlp_w      = (const float*)d_in[5];
    const float* mlp_b      = (const float*)d_in[6];
    float* out = (float*)d_out;

    const size_t M = 16384;                       // B*N rows
    char* ws = (char*)d_ws;
    size_t off = 0;
    unsigned short* tok     = (unsigned short*)(ws + off); off += M * ED * 2;
    unsigned short* w_inP   = (unsigned short*)(ws + off); off += (size_t)3 * ED * ED * 2;
    unsigned short* w_mlp   = (unsigned short*)(ws + off); off += (size_t)ED * ED * 2;
    unsigned short* w_outT  = (unsigned short*)(ws + off); off += (size_t)ED * ED * 2;
    unsigned short* w_comb  = (unsigned short*)(ws + off); off += (size_t)ED * ED * 2;
    unsigned short* w_combP = (unsigned short*)(ws + off); off += (size_t)ED * ED * 2;
    float* zbias            = (float*)(ws + off);          off += ED * 4;
    float* b_comb           = (float*)(ws + off);          off += ED * 4;
    unsigned short* obuf    = (unsigned short*)(ws + off); off += M * ED * 2;
    unsigned short* qkv     = (unsigned short*)(ws + off); off += M * 3 * ED * 2;

    if (ws_size < off) {
        fprintf(stderr, "kernel_launch: ws too small (%zu < %zu)\n", ws_size, off);
        return;
    }

    // weight prep: pack in_proj (fused f32->bf16), convert mlp, transpose out
    pack_w_kernel<1><<<dim3(3 * ED / 64, ED / 64), 512, 0, stream>>>(
        in_proj_w, w_inP, ED);
    {
        int n4 = ED * ED / 4;
        f32_to_bf16_kernel<<<(n4 + 255) / 256, 256, 0, stream>>>(mlp_w, w_mlp, n4);
        transpose_bf16_kernel<<<dim3(ED / 64, ED / 64), 256, 0, stream>>>(
            out_proj_w, w_outT, ED);
        hipMemsetAsync(zbias, 0, ED * sizeof(float), stream);
    }

    // W_comb = mlp_w @ out_proj_w  (row-major [j][k]); then pack
    gemm128<<<dim3(ED / 128, ED / 128), 256, 0, stream>>>(
        w_mlp, w_outT, zbias, w_comb, ED, ED, ED);
    pack_w_kernel<0><<<dim3(ED / 64, ED / 64), 512, 0, stream>>>(
        w_comb, w_combP, ED);
    // b_comb = mlp_w @ out_proj_b + mlp_b
    bcomb_kernel<<<ED / 4, 256, 0, stream>>>(mlp_w, out_proj_b, mlp_b, b_comb);

    // window partition
    partition_kernel<<<(NB * NC * 64 * 64 * 16) / 256, 256, 0, stream>>>(x, tok);

    // qkv = tok @ in_proj_w^T + in_proj_b   (16384 x 6144 x 2048)
    gemm256<1><<<dim3(64 * (6144 / 256)), 512, 0, stream>>>(
        tok, w_inP, in_proj_b, qkv, 16384, 6144, 2048);

    // attention (seq=B=4, batch=N*H)
    attn_kernel<<<NTOK, 512, 0, stream>>>(qkv, obuf);

    // out = reverse(obuf @ W_comb^T + b_comb)  -- scatter epilogue
    gemm256<2><<<dim3(64 * (2048 / 256)), 512, 0, stream>>>(
        obuf, w_combP, b_comb, out, 16384, 2048, 2048);
}

// Round 15
// 687.475 us; speedup vs baseline: 1.0859x; 1.0842x over previous
//
#include <hip/hip_runtime.h>
#include <stdio.h>

// ---------------------------------------------------------------------------
// WindowAttention: partition -> QKV gemm -> attention over B axis ->
// fused (out_proj @ mlp) gemm with window-reverse scatter epilogue.
// GEMM: 256x256 tile, SIXTEEN waves (4m x 4n, 64x64 each) @ 1024 thr/block:
// acc 64 VGPR -> <=128 total -> 16 waves/CU (4/SIMD) = 2x TLP vs r8.
// 16x16x32 MFMA, LDS A+B double-buffered (128KB), r4-proven 2-region sync.
// ---------------------------------------------------------------------------

typedef __attribute__((ext_vector_type(4))) float f32x4;
typedef __attribute__((ext_vector_type(8))) short s16x8;
typedef __attribute__((ext_vector_type(2))) unsigned short u16x2;
typedef __attribute__((ext_vector_type(4))) unsigned short u16x4;

#define NB 4        // batch B (attention seq len)
#define NC 32       // channels
#define NTOK 4096   // N = 16^3 windows
#define ED 2048     // embed dim E
#define NH 16       // heads
#define HD 128      // head dim

__device__ __forceinline__ unsigned short f2bf(float f) {
    union { float f; unsigned int u; } v; v.f = f;
    unsigned int r = (v.u + 0x7fffu + ((v.u >> 16) & 1u)) >> 16;
    return (unsigned short)r;
}
__device__ __forceinline__ float bf2f(unsigned short u) {
    union { unsigned int u; float f; } v; v.u = ((unsigned int)u) << 16;
    return v.f;
}

#define BARRIER() asm volatile("s_barrier" ::: "memory")
#define LGKM0() do { asm volatile("s_waitcnt lgkmcnt(0)" ::: "memory"); \
                     __builtin_amdgcn_sched_barrier(0); } while (0)
#define VMCNT(n) asm volatile("s_waitcnt vmcnt(" #n ")" ::: "memory")

// ---------------- fp32 -> bf16 convert (weights) ----------------
__global__ void f32_to_bf16_kernel(const float* __restrict__ src,
                                   unsigned short* __restrict__ dst, int n4) {
    int i = blockIdx.x * blockDim.x + threadIdx.x;
    if (i >= n4) return;
    f32x4 v = *(const f32x4*)(src + (size_t)i * 4);
    u16x4 w;
    w.x = f2bf(v.x); w.y = f2bf(v.y); w.z = f2bf(v.z); w.w = f2bf(v.w);
    *(u16x4*)(dst + (size_t)i * 4) = w;
}

// ---------------- transpose f32 -> bf16: dst[j,k] = src[k,j] ----------------
__global__ __launch_bounds__(256) void transpose_bf16_kernel(
    const float* __restrict__ src, unsigned short* __restrict__ dst, int n) {
    __shared__ float lds[64][68];
    const int bx = blockIdx.x * 64;   // j base
    const int by = blockIdx.y * 64;   // k base
    const int t  = threadIdx.x;
    const int r  = t >> 2;            // 0..63
    const int c4 = (t & 3) * 16;      // 0/16/32/48
    const float* s = src + (size_t)(by + r) * n + bx + c4;
    #pragma unroll
    for (int i = 0; i < 4; ++i)
        *(f32x4*)&lds[r][c4 + i * 4] = *(const f32x4*)(s + i * 4);
    __syncthreads();
    unsigned short* d = dst + (size_t)(bx + r) * n + by + c4;
    #pragma unroll
    for (int i = 0; i < 4; ++i) {
        u16x4 w;
        w.x = f2bf(lds[c4 + i * 4 + 0][r]);
        w.y = f2bf(lds[c4 + i * 4 + 1][r]);
        w.z = f2bf(lds[c4 + i * 4 + 2][r]);
        w.w = f2bf(lds[c4 + i * 4 + 3][r]);
        *(u16x4*)(d + i * 4) = w;
    }
}

// ---------------- b_comb = mlp_w @ out_proj_b + mlp_b (wave per row) -------
__global__ __launch_bounds__(256) void bcomb_kernel(
    const float* __restrict__ mlp_w, const float* __restrict__ opb,
    const float* __restrict__ mlpb, float* __restrict__ bcomb) {
    const int wave = threadIdx.x >> 6, lane = threadIdx.x & 63;
    const int row = blockIdx.x * 4 + wave;
    const float* r = mlp_w + (size_t)row * ED;
    float s = 0.0f;
    for (int k = lane * 4; k < ED; k += 256) {
        f32x4 a = *(const f32x4*)(r + k);
        f32x4 b = *(const f32x4*)(opb + k);
        s += a.x * b.x + a.y * b.y + a.z * b.z + a.w * b.w;
    }
    #pragma unroll
    for (int off = 32; off > 0; off >>= 1) s += __shfl_xor(s, off, 64);
    if (lane == 0) bcomb[row] = s + mlpb[row];
}

// ---------------- window partition: x -> tok (B,N,E) bf16 ----------------
__global__ void partition_kernel(const float* __restrict__ x,
                                 unsigned short* __restrict__ tok) {
    int idx = blockIdx.x * blockDim.x + threadIdx.x;
    int m = idx & 15;
    int t = idx >> 4;
    int Y = t & 63; t >>= 6;
    int X = t & 63; t >>= 6;
    int c = t & 31;
    int b = t >> 5;
    f32x4 xv = *(const f32x4*)(x + (size_t)idx * 4);
    int nx = X >> 2, px = X & 3;
    int ny = Y >> 2, py = Y & 3;
    int n = nx * 256 + ny * 16 + m;
    int e = c * 64 + px * 16 + py * 4;
    size_t dst = (size_t)(b * NTOK + n) * ED + e;
    u16x4 w;
    w.x = f2bf(xv.x); w.y = f2bf(xv.y); w.z = f2bf(xv.z); w.w = f2bf(xv.w);
    *(u16x4*)&tok[dst] = w;
}

// ---------------- 128x128 4-wave bf16 GEMM (for small W_comb job) ----------
__global__ __launch_bounds__(256) void gemm128(
    const unsigned short* __restrict__ A,   // M x K bf16
    const unsigned short* __restrict__ W,   // Nout x K bf16
    const float* __restrict__ bias,         // Nout f32
    unsigned short* __restrict__ C,         // M x Nout bf16
    int M, int Nout, int K)
{
    __shared__ unsigned short ldsA[128 * 64];
    __shared__ unsigned short ldsW[128 * 64];

    const int tid  = threadIdx.x;
    const int wave = tid >> 6;
    const int lane = tid & 63;
    const int bm = blockIdx.x * 128;
    const int bn = blockIdx.y * 128;
    const int wm = (wave >> 1) * 64;
    const int wn = (wave & 1) * 64;

    f32x4 acc[4][4] = {};

    const int srow = lane >> 3;
    const int scol = (lane & 7) * 8;
    const int lrow = lane & 15;
    const int lk   = (lane >> 4) * 8;

    const int nkt = K >> 6;
    for (int kt = 0; kt < nkt; ++kt) {
        const int kbase = kt * 64;
        #pragma unroll
        for (int q = 0; q < 4; ++q) {
            int chunk = wave * 4 + q;
            int row = chunk * 8 + srow;
            const unsigned short* ga = A + (size_t)(bm + row) * K + kbase + scol;
            const unsigned short* gw = W + (size_t)(bn + row) * K + kbase + scol;
            __builtin_amdgcn_global_load_lds(
                (const __attribute__((address_space(1))) void*)ga,
                (__attribute__((address_space(3))) void*)(&ldsA[chunk * 512]),
                16, 0, 0);
            __builtin_amdgcn_global_load_lds(
                (const __attribute__((address_space(1))) void*)gw,
                (__attribute__((address_space(3))) void*)(&ldsW[chunk * 512]),
                16, 0, 0);
        }
        __syncthreads();

        #pragma unroll
        for (int ks = 0; ks < 2; ++ks) {
            const int k0 = ks * 32 + lk;
            s16x8 af[4], bf[4];
            #pragma unroll
            for (int m = 0; m < 4; ++m)
                af[m] = *(const s16x8*)&ldsA[(wm + m * 16 + lrow) * 64 + k0];
            #pragma unroll
            for (int n = 0; n < 4; ++n)
                bf[n] = *(const s16x8*)&ldsW[(wn + n * 16 + lrow) * 64 + k0];
            #pragma unroll
            for (int m = 0; m < 4; ++m)
                #pragma unroll
                for (int n = 0; n < 4; ++n)
                    acc[m][n] = __builtin_amdgcn_mfma_f32_16x16x32_bf16(
                        af[m], bf[n], acc[m][n], 0, 0, 0);
        }
        __syncthreads();
    }

    const int col   = lane & 15;
    const int rbase = (lane >> 4) * 4;
    #pragma unroll
    for (int n = 0; n < 4; ++n) {
        int cc = bn + wn + n * 16 + col;
        float bv = bias[cc];
        #pragma unroll
        for (int m = 0; m < 4; ++m)
            #pragma unroll
            for (int r = 0; r < 4; ++r) {
                int rr = bm + wm + m * 16 + rbase + r;
                C[(size_t)rr * Nout + cc] = f2bf(acc[m][n][r] + bv);
            }
    }
}

// ---------------- 256x256 16-wave bf16 GEMM (high-occupancy) ----------------
// C[r,j] = sum_k A[r,k] * W[j,k] + bias[j].  M == 16384, Nout % 1024 == 0.
// 1024 threads = 16 waves (4m x 4n), per-wave 64x64 -> acc 64 VGPR, total
// <=128 -> 16 waves/CU (4/SIMD).  BK=64, LDS A+B 2-deep = 128KB.
// Per tile t (db=t&1):
//  regA: read kh0 frags (8 ds); stage B(t+1)->db^1 (2); lgkm0; 16 MFMA kh0
//  regB: read kh1 frags (8 ds); lgkm0; BAR#1 (all db reads done);
//        stage A(t+2)->db (2); 16 MFMA kh1; vmcnt(2) [only A(t+2) rides];
//        BAR#2 (tile t+1 resident)
// OUT_MODE: 1 = bf16 row-major; 2 = f32 window-reverse scatter.
template <int OUT_MODE>
__global__ __launch_bounds__(1024, 4) void gemm256(
    const unsigned short* __restrict__ A,   // M x K bf16
    const unsigned short* __restrict__ W,   // Nout x K bf16
    const float* __restrict__ bias,         // Nout f32
    void* __restrict__ Cv,                  // out per OUT_MODE
    int M, int Nout, int K)
{
    __shared__ unsigned short ldsA[2][256 * 64];
    __shared__ unsigned short ldsB[2][256 * 64];

    const int tid  = threadIdx.x;
    const int wave = tid >> 6;          // 0..15
    const int lane = tid & 63;

    // L2-locality mapping (bijective, gm=64): XCD x owns m-band x; 8m x 4n
    // macro-tiles of 32 blocks.
    const int f   = blockIdx.x;
    const int xcd = f & 7;
    const int r_  = f >> 3;
    const int mac = r_ >> 5;
    const int w_  = r_ & 31;
    const int bm  = (xcd * 8 + (w_ & 7)) * 256;
    const int bn  = (mac * 4 + (w_ >> 3)) * 256;

    const int wi   = wave >> 2;         // 0-3: m quarter (64 rows)
    const int wj   = wave & 3;          // 0-3: n quarter (64 cols)
    const int lrow = lane & 15;
    const int kq   = lane >> 4;                    // 0-3
    const int s0   = ((kq ^ (lrow & 7)) << 3);     // swizzled elem off (kh0)
    const int s1   = s0 ^ 32;                      // kh1

    f32x4 acc[4][4] = {};

    const int nkt = K >> 6;

    const int srl   = lane >> 3;                         // 0-7
    const int sslot = (((lane & 7) ^ srl) << 3);         // pre-swizzled src off

    // staging: 2 instrs per matrix per tile per wave (chunk = 8 rows)
    auto stA = [&](int db, int tt) {
        const unsigned short* gb = A + (size_t)bm * K + tt * 64;
        unsigned short* lb = &ldsA[db][0];
        #pragma unroll
        for (int q = 0; q < 2; ++q) {
            const int r0 = (wave * 2 + q) * 8;
            const unsigned short* ga = gb + (size_t)(r0 + srl) * K + sslot;
            __builtin_amdgcn_global_load_lds(
                (const __attribute__((address_space(1))) void*)ga,
                (__attribute__((address_space(3))) void*)(lb + r0 * 64),
                16, 0, 0);
        }
    };
    auto stB = [&](int db, int tt) {
        const unsigned short* gb = W + (size_t)bn * K + tt * 64;
        unsigned short* lb = &ldsB[db][0];
        #pragma unroll
        for (int q = 0; q < 2; ++q) {
            const int r0 = (wave * 2 + q) * 8;
            const unsigned short* ga = gb + (size_t)(r0 + srl) * K + sslot;
            __builtin_amdgcn_global_load_lds(
                (const __attribute__((address_space(1))) void*)ga,
                (__attribute__((address_space(3))) void*)(lb + r0 * 64),
                16, 0, 0);
        }
    };

    // ---- prologue: A(0),B(0) -> db0; A(1) -> db1 rides
    stA(0, 0); stB(0, 0);
    stA(1, 1);
    VMCNT(2);
    BARRIER();

    const int arow = wi * 64 + lrow;    // + m*16
    const int brow = wj * 64 + lrow;    // + n*16

    for (int t = 0; t < nkt; ++t) {
        const int db = t & 1;
        const unsigned short* hA = &ldsA[db][0];
        const unsigned short* hB = &ldsB[db][0];

        s16x8 af[4], bf[4];

        // ===== region A: kh0
        #pragma unroll
        for (int m = 0; m < 4; ++m)
            af[m] = *(const s16x8*)&hA[(arow + m * 16) * 64 + s0];
        #pragma unroll
        for (int n = 0; n < 4; ++n)
            bf[n] = *(const s16x8*)&hB[(brow + n * 16) * 64 + s0];
        if (t + 1 < nkt) stB(db ^ 1, t + 1);
        LGKM0();
        __builtin_amdgcn_s_setprio(1);
        #pragma unroll
        for (int m = 0; m < 4; ++m)
            #pragma unroll
            for (int n = 0; n < 4; ++n)
                acc[m][n] = __builtin_amdgcn_mfma_f32_16x16x32_bf16(
                    af[m], bf[n], acc[m][n], 0, 0, 0);
        __builtin_amdgcn_s_setprio(0);
        __builtin_amdgcn_sched_barrier(0);

        // ===== region B: kh1
        #pragma unroll
        for (int m = 0; m < 4; ++m)
            af[m] = *(const s16x8*)&hA[(arow + m * 16) * 64 + s1];
        #pragma unroll
        for (int n = 0; n < 4; ++n)
            bf[n] = *(const s16x8*)&hB[(brow + n * 16) * 64 + s1];
        LGKM0();
        BARRIER();     // #1: all waves done reading tile t buffers
        if (t + 2 < nkt) stA(db, t + 2);
        __builtin_amdgcn_s_setprio(1);
        #pragma unroll
        for (int m = 0; m < 4; ++m)
            #pragma unroll
            for (int n = 0; n < 4; ++n)
                acc[m][n] = __builtin_amdgcn_mfma_f32_16x16x32_bf16(
                    af[m], bf[n], acc[m][n], 0, 0, 0);
        __builtin_amdgcn_s_setprio(0);
        if (t + 2 < nkt)      { VMCNT(2); }   // only A(t+2) rides
        else                  { VMCNT(0); }   // tail drain
        BARRIER();     // #2: tile t+1 resident everywhere
    }

    // ---- epilogue: C/D layout col=lane&15, row=(lane>>4)*4+reg
    const int col     = lane & 15;
    const int rbase   = (lane >> 4) * 4;
    const int rowbase = bm + wi * 64;
    const int colbase = bn + wj * 64 + col;
    float bv[4];
    #pragma unroll
    for (int n = 0; n < 4; ++n) bv[n] = bias[colbase + n * 16];

    if (OUT_MODE == 1) {
        unsigned short* C = (unsigned short*)Cv;
        #pragma unroll
        for (int m = 0; m < 4; ++m) {
            #pragma unroll
            for (int r = 0; r < 4; ++r) {
                const int rr = rowbase + m * 16 + rbase + r;
                #pragma unroll
                for (int n = 0; n < 4; ++n)
                    C[(size_t)rr * Nout + colbase + n * 16] = f2bf(acc[m][n][r] + bv[n]);
            }
        }
    } else {
        // window-reverse scatter: rr=(b,nx,ny,nz), cc=(c,px,py,pz) ->
        // out[b,c, px*16+nx, py*16+ny, pz*16+nz]; 4 regs = nz-consecutive
        float* outp = (float*)Cv;
        #pragma unroll
        for (int n = 0; n < 4; ++n) {
            const int cc = colbase + n * 16;
            const int c  = cc >> 6, px = (cc >> 4) & 3,
                      py = (cc >> 2) & 3, pz = cc & 3;
            #pragma unroll
            for (int m = 0; m < 4; ++m) {
                const int rr0 = rowbase + m * 16 + rbase;
                const int b   = rr0 >> 12, nx = (rr0 >> 8) & 15,
                          ny  = (rr0 >> 4) & 15, nz0 = rr0 & 15;
                float* dst = outp
                    + ((size_t)((b * NC + c) * 64 + px * 16 + nx)) * 4096
                    + (size_t)(py * 16 + ny) * 64 + pz * 16 + nz0;
                f32x4 w = {acc[m][n][0] + bv[n], acc[m][n][1] + bv[n],
                           acc[m][n][2] + bv[n], acc[m][n][3] + bv[n]};
                *(f32x4*)dst = w;
            }
        }
    }
}

// ---------------- attention over B axis: seq=4, batch = N*H ----------------
// block = token n (4096 blocks, 512 thr); wave handles 2 heads; u16x4 loads.
__global__ __launch_bounds__(512) void attn_kernel(
    const unsigned short* __restrict__ qkv, unsigned short* __restrict__ o)
{
    const int n    = blockIdx.x;
    const int wave = threadIdx.x >> 6;
    const int lane = threadIdx.x & 63;
    const int h    = wave * 2 + (lane >> 5);
    const int dl   = (lane & 31) * 4;
    const float scale = 0.0883883476483184405501f;  // 1/sqrt(128)

    float q[4][4], k[4][4], v[4][4];
    #pragma unroll
    for (int b = 0; b < 4; ++b) {
        size_t base = (size_t)(b * NTOK + n) * (3 * ED) + h * HD + dl;
        u16x4 uq = *(const u16x4*)&qkv[base];
        u16x4 uk = *(const u16x4*)&qkv[base + ED];
        u16x4 uv = *(const u16x4*)&qkv[base + 2 * ED];
        #pragma unroll
        for (int i = 0; i < 4; ++i) {
            q[b][i] = bf2f(uq[i]); k[b][i] = bf2f(uk[i]); v[b][i] = bf2f(uv[i]);
        }
    }

    float sc[4][4];
    #pragma unroll
    for (int s = 0; s < 4; ++s) {
        #pragma unroll
        for (int t = 0; t < 4; ++t) {
            float p = q[s][0] * k[t][0] + q[s][1] * k[t][1]
                    + q[s][2] * k[t][2] + q[s][3] * k[t][3];
            #pragma unroll
            for (int off = 16; off > 0; off >>= 1)   // reduce within 32-group
                p += __shfl_xor(p, off, 64);
            sc[s][t] = p * scale;
        }
    }

    #pragma unroll
    for (int s = 0; s < 4; ++s) {
        float mx = fmaxf(fmaxf(sc[s][0], sc[s][1]), fmaxf(sc[s][2], sc[s][3]));
        float e0 = __expf(sc[s][0] - mx);
        float e1 = __expf(sc[s][1] - mx);
        float e2 = __expf(sc[s][2] - mx);
        float e3 = __expf(sc[s][3] - mx);
        float inv = 1.0f / (e0 + e1 + e2 + e3);
        u16x4 ov;
        #pragma unroll
        for (int i = 0; i < 4; ++i) {
            float oo = (e0 * v[0][i] + e1 * v[1][i] + e2 * v[2][i] + e3 * v[3][i]) * inv;
            ov[i] = f2bf(oo);
        }
        *(u16x4*)&o[(size_t)(s * NTOK + n) * ED + h * HD + dl] = ov;
    }
}

// ---------------------------------------------------------------------------
extern "C" void kernel_launch(void* const* d_in, const int* in_sizes, int n_in,
                              void* d_out, int out_size, void* d_ws, size_t ws_size,
                              hipStream_t stream) {
    const float* x          = (const float*)d_in[0];
    const float* in_proj_w  = (const float*)d_in[1];
    const float* in_proj_b  = (const float*)d_in[2];
    const float* out_proj_w = (const float*)d_in[3];
    const float* out_proj_b = (const float*)d_in[4];
    const float* mlp_w      = (const float*)d_in[5];
    const float* mlp_b      = (const float*)d_in[6];
    float* out = (float*)d_out;

    const size_t M = 16384;                       // B*N rows
    char* ws = (char*)d_ws;
    size_t off = 0;
    unsigned short* tok    = (unsigned short*)(ws + off); off += M * ED * 2;
    unsigned short* w_in   = (unsigned short*)(ws + off); off += (size_t)3 * ED * ED * 2;
    unsigned short* w_mlp  = (unsigned short*)(ws + off); off += (size_t)ED * ED * 2;
    unsigned short* w_outT = (unsigned short*)(ws + off); off += (size_t)ED * ED * 2;
    unsigned short* w_comb = (unsigned short*)(ws + off); off += (size_t)ED * ED * 2;
    float* zbias           = (float*)(ws + off);          off += ED * 4;
    float* b_comb          = (float*)(ws + off);          off += ED * 4;
    unsigned short* obuf   = (unsigned short*)(ws + off); off += M * ED * 2;
    unsigned short* qkv    = (unsigned short*)(ws + off); off += M * 3 * ED * 2;

    if (ws_size < off) {
        fprintf(stderr, "kernel_launch: ws too small (%zu < %zu)\n", ws_size, off);
        return;
    }

    // weight converts + transpose
    {
        int n4 = 3 * ED * ED / 4;
        f32_to_bf16_kernel<<<(n4 + 255) / 256, 256, 0, stream>>>(in_proj_w, w_in, n4);
        n4 = ED * ED / 4;
        f32_to_bf16_kernel<<<(n4 + 255) / 256, 256, 0, stream>>>(mlp_w, w_mlp, n4);
        transpose_bf16_kernel<<<dim3(ED / 64, ED / 64), 256, 0, stream>>>(
            out_proj_w, w_outT, ED);
        hipMemsetAsync(zbias, 0, ED * sizeof(float), stream);
    }

    // W_comb = mlp_w @ out_proj_w  (row-major [j][k]); 2048^3, 128^2-tile MFMA
    gemm128<<<dim3(ED / 128, ED / 128), 256, 0, stream>>>(
        w_mlp, w_outT, zbias, w_comb, ED, ED, ED);
    // b_comb = mlp_w @ out_proj_b + mlp_b
    bcomb_kernel<<<ED / 4, 256, 0, stream>>>(mlp_w, out_proj_b, mlp_b, b_comb);

    // window partition
    partition_kernel<<<(NB * NC * 64 * 64 * 16) / 256, 256, 0, stream>>>(x, tok);

    // qkv = tok @ in_proj_w^T + in_proj_b   (16384 x 6144 x 2048)
    gemm256<1><<<dim3(64 * (6144 / 256)), 1024, 0, stream>>>(
        tok, w_in, in_proj_b, qkv, 16384, 6144, 2048);

    // attention (seq=B=4, batch=N*H)
    attn_kernel<<<NTOK, 512, 0, stream>>>(qkv, obuf);

    // out = reverse(obuf @ W_comb^T + b_comb)  -- scatter epilogue
    gemm256<2><<<dim3(64 * (2048 / 256)), 1024, 0, stream>>>(
        obuf, w_comb, b_comb, out, 16384, 2048, 2048);
}